// Round 1
// baseline (1110.038 us; speedup 1.0000x reference)
//
#include <hip/hip_runtime.h>
#include <math.h>

#define NN 100000
#define NE 1600000
#define DD 64

__device__ __forceinline__ float gelu_exact(float v) {
    return 0.5f * v * (1.0f + erff(v * 0.7071067811865475f));
}

// order-preserving float <-> uint for atomicMax on signed floats
__device__ __forceinline__ unsigned fkey(float f) {
    unsigned u = __float_as_uint(f);
    return (u & 0x80000000u) ? ~u : (u | 0x80000000u);
}
__device__ __forceinline__ float funkey(unsigned k) {
    unsigned u = (k & 0x80000000u) ? (k ^ 0x80000000u) : ~k;
    return __uint_as_float(u);
}

// K1: per-node prep: s1 = x.att_w[:D], s2 = x.att_w[D:], z = alpha*(x@Wp^T), y = (1-alpha)*(x@Wn^T)
__global__ __launch_bounds__(256) void k1_nodeprep(
    const float* __restrict__ x, const float* __restrict__ attw,
    const float* __restrict__ Wp, const float* __restrict__ Wn,
    const float* __restrict__ cf,
    float* __restrict__ z, float* __restrict__ y,
    float* __restrict__ s1, float* __restrict__ s2)
{
    int n = blockIdx.x * blockDim.x + threadIdx.x;
    if (n >= NN) return;
    float alpha = 1.0f / (1.0f + __expf(-cf[0]));
    float beta = 1.0f - alpha;

    float xr[DD];
    const float4* x4 = (const float4*)(x + (size_t)n * DD);
    #pragma unroll
    for (int i = 0; i < DD/4; ++i) {
        float4 v = x4[i];
        xr[4*i+0] = v.x; xr[4*i+1] = v.y; xr[4*i+2] = v.z; xr[4*i+3] = v.w;
    }

    {
        float a0=0,a1=0,a2=0,a3=0,b0=0,b1=0,b2=0,b3=0;
        #pragma unroll
        for (int k = 0; k < DD; k += 4) {
            a0 += xr[k+0]*attw[k+0]; a1 += xr[k+1]*attw[k+1];
            a2 += xr[k+2]*attw[k+2]; a3 += xr[k+3]*attw[k+3];
            b0 += xr[k+0]*attw[DD+k+0]; b1 += xr[k+1]*attw[DD+k+1];
            b2 += xr[k+2]*attw[DD+k+2]; b3 += xr[k+3]*attw[DD+k+3];
        }
        s1[n] = (a0+a1)+(a2+a3);
        s2[n] = (b0+b1)+(b2+b3);
    }

    // z = alpha * x @ Wp^T   (4 output rows per iteration; W access is uniform -> s_load)
    float4* z4 = (float4*)(z + (size_t)n * DD);
    for (int dq = 0; dq < DD/4; ++dq) {
        const float* wr0 = Wp + (size_t)(4*dq+0)*DD;
        const float* wr1 = Wp + (size_t)(4*dq+1)*DD;
        const float* wr2 = Wp + (size_t)(4*dq+2)*DD;
        const float* wr3 = Wp + (size_t)(4*dq+3)*DD;
        float4 acc = make_float4(0.f,0.f,0.f,0.f);
        #pragma unroll
        for (int k = 0; k < DD; ++k) {
            acc.x += xr[k]*wr0[k]; acc.y += xr[k]*wr1[k];
            acc.z += xr[k]*wr2[k]; acc.w += xr[k]*wr3[k];
        }
        acc.x *= alpha; acc.y *= alpha; acc.z *= alpha; acc.w *= alpha;
        z4[dq] = acc;
    }
    // y = (1-alpha) * x @ Wn^T
    float4* y4 = (float4*)(y + (size_t)n * DD);
    for (int dq = 0; dq < DD/4; ++dq) {
        const float* wr0 = Wn + (size_t)(4*dq+0)*DD;
        const float* wr1 = Wn + (size_t)(4*dq+1)*DD;
        const float* wr2 = Wn + (size_t)(4*dq+2)*DD;
        const float* wr3 = Wn + (size_t)(4*dq+3)*DD;
        float4 acc = make_float4(0.f,0.f,0.f,0.f);
        #pragma unroll
        for (int k = 0; k < DD; ++k) {
            acc.x += xr[k]*wr0[k]; acc.y += xr[k]*wr1[k];
            acc.z += xr[k]*wr2[k]; acc.w += xr[k]*wr3[k];
        }
        acc.x *= beta; acc.y *= beta; acc.z *= beta; acc.w *= beta;
        y4[dq] = acc;
    }
}

// K2: per-edge score + segment max (atomicMax on ordered-uint)
__global__ __launch_bounds__(256) void k2_score(
    const int* __restrict__ ei, const float* __restrict__ s1,
    const float* __restrict__ s2, float* __restrict__ score,
    unsigned* __restrict__ segmax)
{
    int e = blockIdx.x * blockDim.x + threadIdx.x;
    if (e >= NE) return;
    int src = ei[e];
    int dst = ei[NE + e];
    float s = s1[src] + s2[dst];
    score[e] = s;
    atomicMax(segmax + dst, fkey(s));
}

// K3: per-edge exp(score - max) + segment sum of denom
__global__ __launch_bounds__(256) void k3_exp(
    const int* __restrict__ ei, const float* __restrict__ score,
    const unsigned* __restrict__ segmax, float* __restrict__ ev,
    float* __restrict__ denom)
{
    int e = blockIdx.x * blockDim.x + threadIdx.x;
    if (e >= NE) return;
    int dst = ei[NE + e];
    float m = funkey(segmax[dst]);
    float v = expf(score[e] - m);
    ev[e] = v;
    atomicAdd(denom + dst, v);
}

// K4: wave-per-edge weighted scatter-add: agg[dst] += att*(rf*z[src] + y[src])
__global__ __launch_bounds__(256) void k4_agg(
    const int* __restrict__ ei, const float* __restrict__ rf,
    const float* __restrict__ z, const float* __restrict__ y,
    const float* __restrict__ ev, const float* __restrict__ denom,
    float* __restrict__ agg)
{
    int wid = (int)((blockIdx.x * (unsigned)blockDim.x + threadIdx.x) >> 6);
    int lane = threadIdx.x & 63;
    if (wid >= NE) return;
    int src = ei[wid];
    int dst = ei[NE + wid];
    float att = ev[wid] / denom[dst];
    float wp = att * rf[wid];
    float v = wp * z[(size_t)src*DD + lane] + att * y[(size_t)src*DD + lane];
    atomicAdd(agg + (size_t)dst*DD + lane, v);
}

// K5: fused node epilogue: gelu(agg)+x -> LN1 -> MLP(64->128->64, exact gelu) -> +h -> LN2
__global__ __launch_bounds__(256) void k5_node(
    const float* __restrict__ agg, const float* __restrict__ x,
    const float* __restrict__ w1, const float* __restrict__ bb1,
    const float* __restrict__ w2, const float* __restrict__ bb2,
    const float* __restrict__ g1, const float* __restrict__ be1,
    const float* __restrict__ g2, const float* __restrict__ be2,
    float* __restrict__ out)
{
    int n = blockIdx.x * blockDim.x + threadIdx.x;
    if (n >= NN) return;

    float h[DD];
    const float4* a4 = (const float4*)(agg + (size_t)n * DD);
    const float4* x4 = (const float4*)(x + (size_t)n * DD);
    #pragma unroll
    for (int i = 0; i < DD/4; ++i) {
        float4 av = a4[i];
        float4 xv = x4[i];
        h[4*i+0] = gelu_exact(av.x) + xv.x;
        h[4*i+1] = gelu_exact(av.y) + xv.y;
        h[4*i+2] = gelu_exact(av.z) + xv.z;
        h[4*i+3] = gelu_exact(av.w) + xv.w;
    }

    // LN1
    {
        float mu = 0.f;
        #pragma unroll
        for (int d = 0; d < DD; ++d) mu += h[d];
        mu *= (1.0f/DD);
        float var = 0.f;
        #pragma unroll
        for (int d = 0; d < DD; ++d) { float t = h[d]-mu; var += t*t; }
        var *= (1.0f/DD);
        float rs = rsqrtf(var + 1e-5f);
        #pragma unroll
        for (int d = 0; d < DD; ++d) h[d] = (h[d]-mu)*rs*g1[d] + be1[d];
    }

    // MLP: m = gelu(h@w1^T + b1) @ w2^T + b2
    float m[DD];
    #pragma unroll
    for (int d = 0; d < DD; ++d) m[d] = bb2[d];
    for (int j = 0; j < 2*DD; ++j) {
        const float* wr = w1 + (size_t)j*DD;
        float t0=0.f,t1=0.f,t2=0.f,t3=0.f;
        #pragma unroll
        for (int k = 0; k < DD; k += 4) {
            t0 += h[k+0]*wr[k+0]; t1 += h[k+1]*wr[k+1];
            t2 += h[k+2]*wr[k+2]; t3 += h[k+3]*wr[k+3];
        }
        float t = (t0+t1)+(t2+t3) + bb1[j];
        float g = gelu_exact(t);
        #pragma unroll
        for (int d = 0; d < DD; ++d) m[d] += g * w2[(size_t)d*(2*DD) + j];
    }

    // residual + LN2
    {
        #pragma unroll
        for (int d = 0; d < DD; ++d) m[d] += h[d];
        float mu = 0.f;
        #pragma unroll
        for (int d = 0; d < DD; ++d) mu += m[d];
        mu *= (1.0f/DD);
        float var = 0.f;
        #pragma unroll
        for (int d = 0; d < DD; ++d) { float t = m[d]-mu; var += t*t; }
        var *= (1.0f/DD);
        float rs = rsqrtf(var + 1e-5f);
        float4* o4 = (float4*)(out + (size_t)n * DD);
        #pragma unroll
        for (int i = 0; i < DD/4; ++i) {
            float4 o;
            o.x = (m[4*i+0]-mu)*rs*g2[4*i+0] + be2[4*i+0];
            o.y = (m[4*i+1]-mu)*rs*g2[4*i+1] + be2[4*i+1];
            o.z = (m[4*i+2]-mu)*rs*g2[4*i+2] + be2[4*i+2];
            o.w = (m[4*i+3]-mu)*rs*g2[4*i+3] + be2[4*i+3];
            o4[i] = o;
        }
    }
}

extern "C" void kernel_launch(void* const* d_in, const int* in_sizes, int n_in,
                              void* d_out, int out_size, void* d_ws, size_t ws_size,
                              hipStream_t stream) {
    const float* x    = (const float*)d_in[0];
    const int*   ei   = (const int*)d_in[1];
    const float* rf   = (const float*)d_in[2];
    const float* Wp   = (const float*)d_in[3];
    const float* Wn   = (const float*)d_in[4];
    const float* attw = (const float*)d_in[5];
    const float* cf   = (const float*)d_in[6];
    const float* w1   = (const float*)d_in[7];
    const float* b1   = (const float*)d_in[8];
    const float* w2   = (const float*)d_in[9];
    const float* b2   = (const float*)d_in[10];
    const float* g1   = (const float*)d_in[11];
    const float* be1  = (const float*)d_in[12];
    const float* g2   = (const float*)d_in[13];
    const float* be2  = (const float*)d_in[14];
    float* out = (float*)d_out;

    float* ws = (float*)d_ws;
    float* z      = ws;                                   // NN*DD
    float* yy     = z  + (size_t)NN*DD;                   // NN*DD
    float* agg    = yy + (size_t)NN*DD;                   // NN*DD
    unsigned* segmax = (unsigned*)(agg + (size_t)NN*DD);  // NN
    float* denom  = (float*)(segmax + NN);                // NN
    float* s1     = denom + NN;                           // NN
    float* s2     = s1 + NN;                              // NN
    float* score  = s2 + NN;                              // NE
    float* ev     = score + NE;                           // NE

    // zero agg + segmax + denom (contiguous); key 0 decodes below any real score
    hipMemsetAsync(agg, 0, ((size_t)NN*DD + 2*(size_t)NN) * sizeof(float), stream);

    k1_nodeprep<<<(NN+255)/256, 256, 0, stream>>>(x, attw, Wp, Wn, cf, z, yy, s1, s2);
    k2_score   <<<(NE+255)/256, 256, 0, stream>>>(ei, s1, s2, score, segmax);
    k3_exp     <<<(NE+255)/256, 256, 0, stream>>>(ei, score, segmax, ev, denom);
    k4_agg     <<<NE/4,         256, 0, stream>>>(ei, rf, z, yy, ev, denom, agg);
    k5_node    <<<(NN+255)/256, 256, 0, stream>>>(agg, x, w1, b1, w2, b2, g1, be1, g2, be2, out);
}

// Round 2
// 1096.359 us; speedup vs baseline: 1.0125x; 1.0125x over previous
//
#include <hip/hip_runtime.h>
#include <math.h>

#define NN 100000
#define NE 1600000
#define DD 64

__device__ __forceinline__ float gelu_exact(float v) {
    return 0.5f * v * (1.0f + erff(v * 0.7071067811865475f));
}

// order-preserving float <-> uint for atomicMax on signed floats
__device__ __forceinline__ unsigned fkey(float f) {
    unsigned u = __float_as_uint(f);
    return (u & 0x80000000u) ? ~u : (u | 0x80000000u);
}
__device__ __forceinline__ float funkey(unsigned k) {
    unsigned u = (k & 0x80000000u) ? (k ^ 0x80000000u) : ~k;
    return __uint_as_float(u);
}

// K0: transpose w2[64][128] -> w2T[128][64] so GEMM2 inner loop is contiguous
__global__ __launch_bounds__(256) void k0_transpose(
    const float* __restrict__ w2, float* __restrict__ w2T)
{
    int t = blockIdx.x * 256 + threadIdx.x;   // 8192
    int j = t & 127;
    int d = t >> 7;
    w2T[j * DD + d] = w2[d * 2 * DD + j];
}

// K1: wave-parallel node prep. Block = 64 nodes x 4 waves.
// Wave q computes output dims [16q,16q+16) of z = alpha*x@Wp^T and y = (1-alpha)*x@Wn^T.
// Wave 0 additionally computes s1 = x.att_w[:D], s2 = x.att_w[D:].
__global__ __launch_bounds__(256) void k1_nodeprep(
    const float* __restrict__ x, const float* __restrict__ attw,
    const float* __restrict__ Wp, const float* __restrict__ Wn,
    const float* __restrict__ cf,
    float* __restrict__ z, float* __restrict__ y,
    float* __restrict__ s1, float* __restrict__ s2)
{
    int lane = threadIdx.x & 63;
    int q    = threadIdx.x >> 6;          // wave id 0..3 (uniform per wave)
    int n    = blockIdx.x * 64 + lane;
    if (n >= NN) return;                  // no barriers in this kernel

    float alpha = 1.0f / (1.0f + __expf(-cf[0]));
    float beta  = 1.0f - alpha;

    float xr[DD];
    const float4* x4 = (const float4*)(x + (size_t)n * DD);
    #pragma unroll
    for (int i = 0; i < DD/4; ++i) {
        float4 v = x4[i];
        xr[4*i+0] = v.x; xr[4*i+1] = v.y; xr[4*i+2] = v.z; xr[4*i+3] = v.w;
    }

    if (q == 0) {
        float a0=0,a1=0,b0=0,b1=0;
        #pragma unroll
        for (int k = 0; k < DD; k += 2) {
            a0 += xr[k+0]*attw[k+0];    a1 += xr[k+1]*attw[k+1];
            b0 += xr[k+0]*attw[DD+k+0]; b1 += xr[k+1]*attw[DD+k+1];
        }
        s1[n] = a0+a1;
        s2[n] = b0+b1;
    }

    int d0 = q * 16;                      // wave-uniform output slice
    // z slice
    for (int dd = 0; dd < 16; dd += 4) {
        const float* wr0 = Wp + (size_t)(d0+dd+0)*DD;
        const float* wr1 = Wp + (size_t)(d0+dd+1)*DD;
        const float* wr2 = Wp + (size_t)(d0+dd+2)*DD;
        const float* wr3 = Wp + (size_t)(d0+dd+3)*DD;
        float4 acc = make_float4(0.f,0.f,0.f,0.f);
        #pragma unroll
        for (int k = 0; k < DD; ++k) {
            acc.x += xr[k]*wr0[k]; acc.y += xr[k]*wr1[k];
            acc.z += xr[k]*wr2[k]; acc.w += xr[k]*wr3[k];
        }
        acc.x *= alpha; acc.y *= alpha; acc.z *= alpha; acc.w *= alpha;
        *(float4*)(z + (size_t)n*DD + d0 + dd) = acc;
    }
    // y slice
    for (int dd = 0; dd < 16; dd += 4) {
        const float* wr0 = Wn + (size_t)(d0+dd+0)*DD;
        const float* wr1 = Wn + (size_t)(d0+dd+1)*DD;
        const float* wr2 = Wn + (size_t)(d0+dd+2)*DD;
        const float* wr3 = Wn + (size_t)(d0+dd+3)*DD;
        float4 acc = make_float4(0.f,0.f,0.f,0.f);
        #pragma unroll
        for (int k = 0; k < DD; ++k) {
            acc.x += xr[k]*wr0[k]; acc.y += xr[k]*wr1[k];
            acc.z += xr[k]*wr2[k]; acc.w += xr[k]*wr3[k];
        }
        acc.x *= beta; acc.y *= beta; acc.z *= beta; acc.w *= beta;
        *(float4*)(y + (size_t)n*DD + d0 + dd) = acc;
    }
}

// K2: per-edge score + segment max (atomicMax on ordered-uint)
__global__ __launch_bounds__(256) void k2_score(
    const int* __restrict__ ei, const float* __restrict__ s1,
    const float* __restrict__ s2, float* __restrict__ score,
    unsigned* __restrict__ segmax)
{
    int e = blockIdx.x * blockDim.x + threadIdx.x;
    if (e >= NE) return;
    int src = ei[e];
    int dst = ei[NE + e];
    float s = s1[src] + s2[dst];
    score[e] = s;
    atomicMax(segmax + dst, fkey(s));
}

// K3: per-edge exp(score - max) + segment sum of denom
__global__ __launch_bounds__(256) void k3_exp(
    const int* __restrict__ ei, const float* __restrict__ score,
    const unsigned* __restrict__ segmax, float* __restrict__ ev,
    float* __restrict__ denom)
{
    int e = blockIdx.x * blockDim.x + threadIdx.x;
    if (e >= NE) return;
    int dst = ei[NE + e];
    float m = funkey(segmax[dst]);
    float v = expf(score[e] - m);
    ev[e] = v;
    atomicAdd(denom + dst, v);
}

// K4: wave-per-edge weighted scatter-add: agg[dst] += att*(rf*z[src] + y[src])
__global__ __launch_bounds__(256) void k4_agg(
    const int* __restrict__ ei, const float* __restrict__ rf,
    const float* __restrict__ z, const float* __restrict__ y,
    const float* __restrict__ ev, const float* __restrict__ denom,
    float* __restrict__ agg)
{
    int wid = (int)((blockIdx.x * (unsigned)blockDim.x + threadIdx.x) >> 6);
    int lane = threadIdx.x & 63;
    if (wid >= NE) return;
    int src = ei[wid];
    int dst = ei[NE + wid];
    float att = ev[wid] / denom[dst];
    float wp = att * rf[wid];
    float v = wp * z[(size_t)src*DD + lane] + att * y[(size_t)src*DD + lane];
    atomicAdd(agg + (size_t)dst*DD + lane, v);
}

// K5: wave-parallel fused node epilogue. Block = 64 nodes x 4 waves.
// Each wave computes h = LN1(gelu(agg)+x) for its lane's node (redundant but
// coalesced), then the j-quarter [32q,32q+32) of the MLP hidden layer,
// accumulating a partial m[64]. Waves 1-3 spill partials to LDS; wave 0
// reduces, adds residual + b2, applies LN2, stores.
__global__ __launch_bounds__(256) void k5_node(
    const float* __restrict__ agg, const float* __restrict__ x,
    const float* __restrict__ w1, const float* __restrict__ bb1,
    const float* __restrict__ w2T, const float* __restrict__ bb2,
    const float* __restrict__ g1, const float* __restrict__ be1,
    const float* __restrict__ g2, const float* __restrict__ be2,
    float* __restrict__ out)
{
    __shared__ float part[3 * 64 * 65];   // padded rows: stride 65 -> conflict-free

    int lane = threadIdx.x & 63;
    int q    = threadIdx.x >> 6;          // wave id, uniform per wave
    int n    = blockIdx.x * 64 + lane;
    bool ok  = (n < NN);

    float h[DD];
    if (ok) {
        const float4* a4 = (const float4*)(agg + (size_t)n * DD);
        const float4* x4 = (const float4*)(x   + (size_t)n * DD);
        #pragma unroll
        for (int i = 0; i < DD/4; ++i) {
            float4 av = a4[i];
            float4 xv = x4[i];
            h[4*i+0] = gelu_exact(av.x) + xv.x;
            h[4*i+1] = gelu_exact(av.y) + xv.y;
            h[4*i+2] = gelu_exact(av.z) + xv.z;
            h[4*i+3] = gelu_exact(av.w) + xv.w;
        }
        float mu = 0.f;
        #pragma unroll
        for (int d = 0; d < DD; ++d) mu += h[d];
        mu *= (1.0f/DD);
        float var = 0.f;
        #pragma unroll
        for (int d = 0; d < DD; ++d) { float t = h[d]-mu; var += t*t; }
        var *= (1.0f/DD);
        float rs = rsqrtf(var + 1e-5f);
        #pragma unroll
        for (int d = 0; d < DD; ++d) h[d] = (h[d]-mu)*rs*g1[d] + be1[d];
    } else {
        #pragma unroll
        for (int d = 0; d < DD; ++d) h[d] = 0.f;
    }

    // MLP quarter: j in [32q, 32q+32). Weight addresses wave-uniform -> s_load.
    float m[DD];
    #pragma unroll
    for (int d = 0; d < DD; ++d) m[d] = 0.f;
    int j0 = q * 32;
    for (int jj = 0; jj < 32; ++jj) {
        int j = j0 + jj;
        const float* wr = w1 + (size_t)j * DD;
        float t0=0.f,t1=0.f,t2=0.f,t3=0.f;
        #pragma unroll
        for (int k = 0; k < DD; k += 4) {
            t0 += h[k+0]*wr[k+0]; t1 += h[k+1]*wr[k+1];
            t2 += h[k+2]*wr[k+2]; t3 += h[k+3]*wr[k+3];
        }
        float g = gelu_exact((t0+t1)+(t2+t3) + bb1[j]);
        const float* wt = w2T + (size_t)j * DD;   // contiguous row
        #pragma unroll
        for (int d = 0; d < DD; ++d) m[d] += g * wt[d];
    }

    if (q > 0) {
        float* p = part + ((size_t)(q-1)*64 + lane) * 65;
        #pragma unroll
        for (int d = 0; d < DD; ++d) p[d] = m[d];
    }
    __syncthreads();

    if (q == 0) {
        #pragma unroll
        for (int qq = 0; qq < 3; ++qq) {
            const float* p = part + ((size_t)qq*64 + lane) * 65;
            #pragma unroll
            for (int d = 0; d < DD; ++d) m[d] += p[d];
        }
        // residual + bias + LN2
        #pragma unroll
        for (int d = 0; d < DD; ++d) m[d] += h[d] + bb2[d];
        float mu = 0.f;
        #pragma unroll
        for (int d = 0; d < DD; ++d) mu += m[d];
        mu *= (1.0f/DD);
        float var = 0.f;
        #pragma unroll
        for (int d = 0; d < DD; ++d) { float t = m[d]-mu; var += t*t; }
        var *= (1.0f/DD);
        float rs = rsqrtf(var + 1e-5f);
        if (ok) {
            float4* o4 = (float4*)(out + (size_t)n * DD);
            #pragma unroll
            for (int i = 0; i < DD/4; ++i) {
                float4 o;
                o.x = (m[4*i+0]-mu)*rs*g2[4*i+0] + be2[4*i+0];
                o.y = (m[4*i+1]-mu)*rs*g2[4*i+1] + be2[4*i+1];
                o.z = (m[4*i+2]-mu)*rs*g2[4*i+2] + be2[4*i+2];
                o.w = (m[4*i+3]-mu)*rs*g2[4*i+3] + be2[4*i+3];
                o4[i] = o;
            }
        }
    }
}

extern "C" void kernel_launch(void* const* d_in, const int* in_sizes, int n_in,
                              void* d_out, int out_size, void* d_ws, size_t ws_size,
                              hipStream_t stream) {
    const float* x    = (const float*)d_in[0];
    const int*   ei   = (const int*)d_in[1];
    const float* rf   = (const float*)d_in[2];
    const float* Wp   = (const float*)d_in[3];
    const float* Wn   = (const float*)d_in[4];
    const float* attw = (const float*)d_in[5];
    const float* cf   = (const float*)d_in[6];
    const float* w1   = (const float*)d_in[7];
    const float* b1   = (const float*)d_in[8];
    const float* w2   = (const float*)d_in[9];
    const float* b2   = (const float*)d_in[10];
    const float* g1   = (const float*)d_in[11];
    const float* be1  = (const float*)d_in[12];
    const float* g2   = (const float*)d_in[13];
    const float* be2  = (const float*)d_in[14];
    float* out = (float*)d_out;

    float* ws = (float*)d_ws;
    float* z      = ws;                                   // NN*DD
    float* yy     = z  + (size_t)NN*DD;                   // NN*DD
    float* agg    = yy + (size_t)NN*DD;                   // NN*DD
    unsigned* segmax = (unsigned*)(agg + (size_t)NN*DD);  // NN
    float* denom  = (float*)(segmax + NN);                // NN
    float* s1     = denom + NN;                           // NN
    float* s2     = s1 + NN;                              // NN
    float* score  = s2 + NN;                              // NE
    float* ev     = score + NE;                           // NE
    float* w2T    = ev + NE;                              // 2*DD*DD

    // zero agg + segmax + denom (contiguous); key 0 decodes below any real score
    hipMemsetAsync(agg, 0, ((size_t)NN*DD + 2*(size_t)NN) * sizeof(float), stream);

    k0_transpose<<<32, 256, 0, stream>>>(w2, w2T);
    k1_nodeprep<<<(NN+63)/64,  256, 0, stream>>>(x, attw, Wp, Wn, cf, z, yy, s1, s2);
    k2_score   <<<(NE+255)/256, 256, 0, stream>>>(ei, s1, s2, score, segmax);
    k3_exp     <<<(NE+255)/256, 256, 0, stream>>>(ei, score, segmax, ev, denom);
    k4_agg     <<<NE/4,         256, 0, stream>>>(ei, rf, z, yy, ev, denom, agg);
    k5_node    <<<(NN+63)/64,   256, 0, stream>>>(agg, x, w1, b1, w2T, b2, g1, be1, g2, be2, out);
}

// Round 3
// 904.580 us; speedup vs baseline: 1.2271x; 1.2120x over previous
//
#include <hip/hip_runtime.h>
#include <math.h>

#define NN 100000
#define NE 1600000
#define DD 64

__device__ __forceinline__ float gelu_exact(float v) {
    return 0.5f * v * (1.0f + erff(v * 0.7071067811865475f));
}

// order-preserving float <-> uint for atomicMax on signed floats
__device__ __forceinline__ unsigned fkey(float f) {
    unsigned u = __float_as_uint(f);
    return (u & 0x80000000u) ? ~u : (u | 0x80000000u);
}
__device__ __forceinline__ float funkey(unsigned k) {
    unsigned u = (k & 0x80000000u) ? (k ^ 0x80000000u) : ~k;
    return __uint_as_float(u);
}

// K0: transpose w2[64][128] -> w2T[128][64] so the GEMM2 rows are contiguous
__global__ __launch_bounds__(256) void k0_transpose(
    const float* __restrict__ w2, float* __restrict__ w2T)
{
    int t = blockIdx.x * 256 + threadIdx.x;   // 8192
    int j = t & 127;
    int d = t >> 7;
    w2T[j * DD + d] = w2[d * 2 * DD + j];
}

// K1: thread-per-node prep with LDS-staged weights (broadcast reads).
// s1 = x.att_w[:D], s2 = x.att_w[D:], z = alpha*x@Wp^T, y = (1-alpha)*x@Wn^T.
__global__ __launch_bounds__(256) void k1_nodeprep(
    const float* __restrict__ x, const float* __restrict__ attw,
    const float* __restrict__ Wp, const float* __restrict__ Wn,
    const float* __restrict__ cf,
    float* __restrict__ z, float* __restrict__ y,
    float* __restrict__ s1, float* __restrict__ s2)
{
    __shared__ float swp[DD * DD];    // 16 KB
    __shared__ float swn[DD * DD];    // 16 KB
    __shared__ float sat[2 * DD];     // 512 B

    int tid = threadIdx.x;
    {
        const float4* gp = (const float4*)Wp;
        const float4* gn = (const float4*)Wn;
        float4* sp = (float4*)swp;
        float4* sn = (float4*)swn;
        #pragma unroll
        for (int i = 0; i < DD*DD/4; i += 256) { sp[i + tid] = gp[i + tid]; sn[i + tid] = gn[i + tid]; }
        if (tid < 2*DD/4) ((float4*)sat)[tid] = ((const float4*)attw)[tid];
    }
    __syncthreads();

    int n = blockIdx.x * 256 + tid;
    if (n >= NN) return;              // no barriers after this point

    float alpha = 1.0f / (1.0f + __expf(-cf[0]));
    float beta  = 1.0f - alpha;

    float xr[DD];
    const float4* x4 = (const float4*)(x + (size_t)n * DD);
    #pragma unroll
    for (int i = 0; i < DD/4; ++i) {
        float4 v = x4[i];
        xr[4*i+0] = v.x; xr[4*i+1] = v.y; xr[4*i+2] = v.z; xr[4*i+3] = v.w;
    }

    {
        float a0=0,a1=0,b0=0,b1=0;
        #pragma unroll
        for (int k = 0; k < DD; k += 2) {
            a0 += xr[k+0]*sat[k+0];    a1 += xr[k+1]*sat[k+1];
            b0 += xr[k+0]*sat[DD+k+0]; b1 += xr[k+1]*sat[DD+k+1];
        }
        s1[n] = a0+a1;
        s2[n] = b0+b1;
    }

    // z = alpha * x @ Wp^T, 4 output dims at a time (LDS rows broadcast)
    float4* z4 = (float4*)(z + (size_t)n * DD);
    for (int d0 = 0; d0 < DD; d0 += 4) {
        float4 acc = make_float4(0.f,0.f,0.f,0.f);
        #pragma unroll
        for (int k = 0; k < DD; k += 4) {
            float4 w0 = *(const float4*)&swp[(d0+0)*DD + k];
            float4 w1v= *(const float4*)&swp[(d0+1)*DD + k];
            float4 w2v= *(const float4*)&swp[(d0+2)*DD + k];
            float4 w3 = *(const float4*)&swp[(d0+3)*DD + k];
            acc.x += xr[k]*w0.x + xr[k+1]*w0.y + xr[k+2]*w0.z + xr[k+3]*w0.w;
            acc.y += xr[k]*w1v.x + xr[k+1]*w1v.y + xr[k+2]*w1v.z + xr[k+3]*w1v.w;
            acc.z += xr[k]*w2v.x + xr[k+1]*w2v.y + xr[k+2]*w2v.z + xr[k+3]*w2v.w;
            acc.w += xr[k]*w3.x + xr[k+1]*w3.y + xr[k+2]*w3.z + xr[k+3]*w3.w;
        }
        acc.x *= alpha; acc.y *= alpha; acc.z *= alpha; acc.w *= alpha;
        z4[d0/4] = acc;
    }
    // y = (1-alpha) * x @ Wn^T
    float4* y4 = (float4*)(y + (size_t)n * DD);
    for (int d0 = 0; d0 < DD; d0 += 4) {
        float4 acc = make_float4(0.f,0.f,0.f,0.f);
        #pragma unroll
        for (int k = 0; k < DD; k += 4) {
            float4 w0 = *(const float4*)&swn[(d0+0)*DD + k];
            float4 w1v= *(const float4*)&swn[(d0+1)*DD + k];
            float4 w2v= *(const float4*)&swn[(d0+2)*DD + k];
            float4 w3 = *(const float4*)&swn[(d0+3)*DD + k];
            acc.x += xr[k]*w0.x + xr[k+1]*w0.y + xr[k+2]*w0.z + xr[k+3]*w0.w;
            acc.y += xr[k]*w1v.x + xr[k+1]*w1v.y + xr[k+2]*w1v.z + xr[k+3]*w1v.w;
            acc.z += xr[k]*w2v.x + xr[k+1]*w2v.y + xr[k+2]*w2v.z + xr[k+3]*w2v.w;
            acc.w += xr[k]*w3.x + xr[k+1]*w3.y + xr[k+2]*w3.z + xr[k+3]*w3.w;
        }
        acc.x *= beta; acc.y *= beta; acc.z *= beta; acc.w *= beta;
        y4[d0/4] = acc;
    }
}

// K2: per-edge score + segment max (atomicMax on ordered-uint)
__global__ __launch_bounds__(256) void k2_score(
    const int* __restrict__ ei, const float* __restrict__ s1,
    const float* __restrict__ s2, float* __restrict__ score,
    unsigned* __restrict__ segmax)
{
    int e = blockIdx.x * blockDim.x + threadIdx.x;
    if (e >= NE) return;
    int src = ei[e];
    int dst = ei[NE + e];
    float s = s1[src] + s2[dst];
    score[e] = s;
    atomicMax(segmax + dst, fkey(s));
}

// K3: per-edge exp(score - max) + segment sum of denom
__global__ __launch_bounds__(256) void k3_exp(
    const int* __restrict__ ei, const float* __restrict__ score,
    const unsigned* __restrict__ segmax, float* __restrict__ ev,
    float* __restrict__ denom)
{
    int e = blockIdx.x * blockDim.x + threadIdx.x;
    if (e >= NE) return;
    int dst = ei[NE + e];
    float m = funkey(segmax[dst]);
    float v = expf(score[e] - m);
    ev[e] = v;
    atomicAdd(denom + dst, v);
}

// K4: wave-per-edge weighted scatter-add: agg[dst] += att*(rf*z[src] + y[src])
__global__ __launch_bounds__(256) void k4_agg(
    const int* __restrict__ ei, const float* __restrict__ rf,
    const float* __restrict__ z, const float* __restrict__ y,
    const float* __restrict__ ev, const float* __restrict__ denom,
    float* __restrict__ agg)
{
    int wid = (int)((blockIdx.x * (unsigned)blockDim.x + threadIdx.x) >> 6);
    int lane = threadIdx.x & 63;
    if (wid >= NE) return;
    int src = ei[wid];
    int dst = ei[NE + wid];
    float att = ev[wid] / denom[dst];
    float wp = att * rf[wid];
    float v = wp * z[(size_t)src*DD + lane] + att * y[(size_t)src*DD + lane];
    atomicAdd(agg + (size_t)dst*DD + lane, v);
}

// K5: thread-per-node fused epilogue with LDS-staged MLP weights.
// h = LN1(gelu(agg)+x); m = gelu(h@w1^T+b1)@w2^T+b2; out = LN2(m+h).
// All weight reads are wave-uniform LDS broadcasts.
__global__ __launch_bounds__(256) void k5_node(
    const float* __restrict__ agg, const float* __restrict__ x,
    const float* __restrict__ w1, const float* __restrict__ bb1,
    const float* __restrict__ w2T, const float* __restrict__ bb2,
    const float* __restrict__ g1, const float* __restrict__ be1,
    const float* __restrict__ g2, const float* __restrict__ be2,
    float* __restrict__ out)
{
    __shared__ float sw1[2*DD * DD];   // 32 KB
    __shared__ float sw2[2*DD * DD];   // 32 KB (transposed w2)
    __shared__ float sb1[2*DD];        // 512 B

    int tid = threadIdx.x;
    {
        const float4* gw1 = (const float4*)w1;
        const float4* gw2 = (const float4*)w2T;
        float4* s1p = (float4*)sw1;
        float4* s2p = (float4*)sw2;
        #pragma unroll
        for (int i = 0; i < 2*DD*DD/4; i += 256) { s1p[i + tid] = gw1[i + tid]; s2p[i + tid] = gw2[i + tid]; }
        if (tid < 2*DD/4) ((float4*)sb1)[tid] = ((const float4*)bb1)[tid];
    }
    __syncthreads();

    int n = blockIdx.x * 256 + tid;
    if (n >= NN) return;               // no barriers after this point

    float h[DD];
    {
        const float4* a4 = (const float4*)(agg + (size_t)n * DD);
        const float4* x4 = (const float4*)(x   + (size_t)n * DD);
        #pragma unroll
        for (int i = 0; i < DD/4; ++i) {
            float4 av = a4[i];
            float4 xv = x4[i];
            h[4*i+0] = gelu_exact(av.x) + xv.x;
            h[4*i+1] = gelu_exact(av.y) + xv.y;
            h[4*i+2] = gelu_exact(av.z) + xv.z;
            h[4*i+3] = gelu_exact(av.w) + xv.w;
        }
        float mu = 0.f;
        #pragma unroll
        for (int d = 0; d < DD; ++d) mu += h[d];
        mu *= (1.0f/DD);
        float var = 0.f;
        #pragma unroll
        for (int d = 0; d < DD; ++d) { float t = h[d]-mu; var += t*t; }
        var *= (1.0f/DD);
        float rs = rsqrtf(var + 1e-5f);
        #pragma unroll
        for (int d = 0; d < DD; ++d) h[d] = (h[d]-mu)*rs*g1[d] + be1[d];
    }

    float m[DD];
    #pragma unroll
    for (int d = 0; d < DD; ++d) m[d] = 0.f;

    #pragma unroll 2
    for (int j = 0; j < 2*DD; ++j) {
        float t0=0.f,t1=0.f,t2=0.f,t3=0.f;
        #pragma unroll
        for (int k = 0; k < DD; k += 4) {
            float4 w = *(const float4*)&sw1[j*DD + k];
            t0 += h[k+0]*w.x; t1 += h[k+1]*w.y;
            t2 += h[k+2]*w.z; t3 += h[k+3]*w.w;
        }
        float g = gelu_exact((t0+t1)+(t2+t3) + sb1[j]);
        #pragma unroll
        for (int k = 0; k < DD; k += 4) {
            float4 w = *(const float4*)&sw2[j*DD + k];
            m[k+0] += g*w.x; m[k+1] += g*w.y;
            m[k+2] += g*w.z; m[k+3] += g*w.w;
        }
    }

    // residual + bias + LN2
    {
        #pragma unroll
        for (int d = 0; d < DD; ++d) m[d] += h[d] + bb2[d];
        float mu = 0.f;
        #pragma unroll
        for (int d = 0; d < DD; ++d) mu += m[d];
        mu *= (1.0f/DD);
        float var = 0.f;
        #pragma unroll
        for (int d = 0; d < DD; ++d) { float t = m[d]-mu; var += t*t; }
        var *= (1.0f/DD);
        float rs = rsqrtf(var + 1e-5f);
        float4* o4 = (float4*)(out + (size_t)n * DD);
        #pragma unroll
        for (int i = 0; i < DD/4; ++i) {
            float4 o;
            o.x = (m[4*i+0]-mu)*rs*g2[4*i+0] + be2[4*i+0];
            o.y = (m[4*i+1]-mu)*rs*g2[4*i+1] + be2[4*i+1];
            o.z = (m[4*i+2]-mu)*rs*g2[4*i+2] + be2[4*i+2];
            o.w = (m[4*i+3]-mu)*rs*g2[4*i+3] + be2[4*i+3];
            o4[i] = o;
        }
    }
}

extern "C" void kernel_launch(void* const* d_in, const int* in_sizes, int n_in,
                              void* d_out, int out_size, void* d_ws, size_t ws_size,
                              hipStream_t stream) {
    const float* x    = (const float*)d_in[0];
    const int*   ei   = (const int*)d_in[1];
    const float* rf   = (const float*)d_in[2];
    const float* Wp   = (const float*)d_in[3];
    const float* Wn   = (const float*)d_in[4];
    const float* attw = (const float*)d_in[5];
    const float* cf   = (const float*)d_in[6];
    const float* w1   = (const float*)d_in[7];
    const float* b1   = (const float*)d_in[8];
    const float* w2   = (const float*)d_in[9];
    const float* b2   = (const float*)d_in[10];
    const float* g1   = (const float*)d_in[11];
    const float* be1  = (const float*)d_in[12];
    const float* g2   = (const float*)d_in[13];
    const float* be2  = (const float*)d_in[14];
    float* out = (float*)d_out;

    float* ws = (float*)d_ws;
    float* z      = ws;                                   // NN*DD
    float* yy     = z  + (size_t)NN*DD;                   // NN*DD
    float* agg    = yy + (size_t)NN*DD;                   // NN*DD
    unsigned* segmax = (unsigned*)(agg + (size_t)NN*DD);  // NN
    float* denom  = (float*)(segmax + NN);                // NN
    float* s1     = denom + NN;                           // NN
    float* s2     = s1 + NN;                              // NN
    float* score  = s2 + NN;                              // NE
    float* ev     = score + NE;                           // NE
    float* w2T    = ev + NE;                              // 2*DD*DD

    // zero agg + segmax + denom (contiguous); key 0 decodes below any real score
    hipMemsetAsync(agg, 0, ((size_t)NN*DD + 2*(size_t)NN) * sizeof(float), stream);

    k0_transpose<<<32, 256, 0, stream>>>(w2, w2T);
    k1_nodeprep<<<(NN+255)/256, 256, 0, stream>>>(x, attw, Wp, Wn, cf, z, yy, s1, s2);
    k2_score   <<<(NE+255)/256, 256, 0, stream>>>(ei, s1, s2, score, segmax);
    k3_exp     <<<(NE+255)/256, 256, 0, stream>>>(ei, score, segmax, ev, denom);
    k4_agg     <<<NE/4,         256, 0, stream>>>(ei, rf, z, yy, ev, denom, agg);
    k5_node    <<<(NN+255)/256, 256, 0, stream>>>(agg, x, w1, b1, w2T, b2, g1, be1, g2, be2, out);
}

// Round 4
// 755.341 us; speedup vs baseline: 1.4696x; 1.1976x over previous
//
#include <hip/hip_runtime.h>
#include <math.h>

#define NN 100000
#define NE 1600000
#define DD 64
#define NB ((NN + 255) / 256)   // 391 scan blocks

__device__ __forceinline__ float gelu_exact(float v) {
    return 0.5f * v * (1.0f + erff(v * 0.7071067811865475f));
}

__device__ __forceinline__ float wave_max64(float v) {
    #pragma unroll
    for (int o = 32; o > 0; o >>= 1) v = fmaxf(v, __shfl_xor(v, o));
    return v;
}
__device__ __forceinline__ float wave_sum64(float v) {
    #pragma unroll
    for (int o = 32; o > 0; o >>= 1) v += __shfl_xor(v, o);
    return v;
}

// K0: transpose w2[64][128] -> w2T[128][64] for k5
__global__ __launch_bounds__(256) void k0_transpose(
    const float* __restrict__ w2, float* __restrict__ w2T)
{
    int t = blockIdx.x * 256 + threadIdx.x;   // 8192
    int j = t & 127;
    int d = t >> 7;
    w2T[j * DD + d] = w2[d * 2 * DD + j];
}

// K1: per-node attention projections only: s1 = x.att_w[:D], s2 = x.att_w[D:]
__global__ __launch_bounds__(256) void k1_scores(
    const float* __restrict__ x, const float* __restrict__ attw,
    float* __restrict__ s1, float* __restrict__ s2)
{
    int n = blockIdx.x * 256 + threadIdx.x;
    if (n >= NN) return;
    const float4* x4 = (const float4*)(x + (size_t)n * DD);
    float a = 0.f, b = 0.f;
    #pragma unroll
    for (int i = 0; i < DD/4; ++i) {
        float4 v = x4[i];
        a += v.x*attw[4*i+0] + v.y*attw[4*i+1] + v.z*attw[4*i+2] + v.w*attw[4*i+3];
        b += v.x*attw[DD+4*i+0] + v.y*attw[DD+4*i+1] + v.z*attw[DD+4*i+2] + v.w*attw[DD+4*i+3];
    }
    s1[n] = a;
    s2[n] = b;
}

// KH: histogram of dst
__global__ __launch_bounds__(256) void kh_hist(
    const int* __restrict__ ei, int* __restrict__ count)
{
    int e = blockIdx.x * 256 + threadIdx.x;
    if (e >= NE) return;
    atomicAdd(count + ei[NE + e], 1);
}

// KSA: per-block exclusive scan of count -> off (block-local), block totals -> bsum
__global__ __launch_bounds__(256) void ks_scanA(
    const int* __restrict__ cnt, int* __restrict__ off, int* __restrict__ bsum)
{
    __shared__ int sa[256], sb[256];
    int t = threadIdx.x;
    int i = blockIdx.x * 256 + t;
    int v = (i < NN) ? cnt[i] : 0;
    sa[t] = v;
    __syncthreads();
    int* s = sa; int* d = sb;
    #pragma unroll
    for (int o = 1; o < 256; o <<= 1) {
        d[t] = s[t] + ((t >= o) ? s[t - o] : 0);
        __syncthreads();
        int* tmp = s; s = d; d = tmp;
    }
    int incl = s[t];
    if (i < NN) off[i] = incl - v;
    if (t == 255) bsum[blockIdx.x] = incl;
}

// KSB: single-block exclusive scan of the NB block sums
__global__ __launch_bounds__(512) void ks_scanB(int* __restrict__ bsum)
{
    __shared__ int sa[512], sb[512];
    int t = threadIdx.x;
    int v = (t < NB) ? bsum[t] : 0;
    sa[t] = v;
    __syncthreads();
    int* s = sa; int* d = sb;
    #pragma unroll
    for (int o = 1; o < 512; o <<= 1) {
        d[t] = s[t] + ((t >= o) ? s[t - o] : 0);
        __syncthreads();
        int* tmp = s; s = d; d = tmp;
    }
    if (t < NB) bsum[t] = s[t] - v;   // exclusive
}

// KSC: add block bases; duplicate into pos; set sentinel off[NN]=NE
__global__ __launch_bounds__(256) void ks_scanC(
    int* __restrict__ off, int* __restrict__ pos, const int* __restrict__ bsum)
{
    int i = blockIdx.x * 256 + threadIdx.x;
    if (i < NN) {
        int o = off[i] + bsum[blockIdx.x];
        off[i] = o;
        pos[i] = o;
    }
    if (i == 0) off[NN] = NE;
}

// KSCAT: scatter edges into dst-sorted order as {src (bits), rf}
__global__ __launch_bounds__(256) void kscat(
    const int* __restrict__ ei, const float* __restrict__ rf,
    int* __restrict__ pos, float2* __restrict__ sorted)
{
    int e = blockIdx.x * 256 + threadIdx.x;
    if (e >= NE) return;
    int src = ei[e];
    int dst = ei[NE + e];
    int p = atomicAdd(pos + dst, 1);
    sorted[p] = make_float2(__int_as_float(src), rf[e]);
}

// K4A: wave-per-node fused softmax + aggregation.
// u = sum_e att*rf*x[src], v = sum_e att*x[src]  (lane = feature dim)
__global__ __launch_bounds__(256) void k4a_agg(
    const float2* __restrict__ sorted, const int* __restrict__ off,
    const float* __restrict__ s1, const float* __restrict__ s2,
    const float* __restrict__ x, float* __restrict__ uv)
{
    int lane = threadIdx.x & 63;
    int n = blockIdx.x * 4 + (threadIdx.x >> 6);   // grid = NN/4 blocks, always valid
    int r0 = off[n], r1 = off[n + 1];
    float s2n = s2[n];

    // online softmax: running max m, denom den
    float m = -INFINITY, den = 0.f;
    for (int base = r0; base < r1; base += 64) {
        int idx = base + lane;
        float sc = -INFINITY;
        if (idx < r1) {
            float2 p = sorted[idx];
            sc = s1[__float_as_int(p.x)] + s2n;
        }
        float cm = wave_max64(sc);
        float nm = fmaxf(m, cm);
        float term = (idx < r1) ? __expf(sc - nm) : 0.f;
        den = den * __expf(m - nm) + wave_sum64(term);
        m = nm;
    }

    // weighted accumulation
    float u = 0.f, v = 0.f;
    for (int base = r0; base < r1; base += 64) {
        int idx = base + lane;
        int cnt = min(64, r1 - base);
        int srcl = 0; float rfl = 0.f, el = 0.f;
        if (idx < r1) {
            float2 p = sorted[idx];
            srcl = __float_as_int(p.x);
            rfl = p.y;
            el = __expf(s1[srcl] + s2n - m);
        }
        for (int j = 0; j < cnt; ++j) {
            int   sj = __shfl(srcl, j);
            float ej = __shfl(el,   j);
            float rj = __shfl(rfl,  j);
            float xv = x[(size_t)sj * DD + lane];
            v += ej * xv;
            u += ej * rj * xv;
        }
    }
    float inv = (r1 > r0) ? 1.f / den : 0.f;
    uv[(size_t)n * 2*DD + lane]      = u * inv;
    uv[(size_t)n * 2*DD + DD + lane] = v * inv;
}

// K4B: thread-per-node matmul: agg = alpha*u@Wp^T + (1-alpha)*v@Wn^T
// (weights LDS-staged, pre-scaled; broadcast reads)
__global__ __launch_bounds__(256) void k4b_mm(
    const float* __restrict__ uv, const float* __restrict__ Wp,
    const float* __restrict__ Wn, const float* __restrict__ cf,
    float* __restrict__ agg)
{
    __shared__ float swp[DD * DD];   // 16 KB, alpha-scaled
    __shared__ float swn[DD * DD];   // 16 KB, beta-scaled

    int tid = threadIdx.x;
    float alpha = 1.0f / (1.0f + __expf(-cf[0]));
    float beta  = 1.0f - alpha;
    {
        const float4* gp = (const float4*)Wp;
        const float4* gn = (const float4*)Wn;
        float4* sp = (float4*)swp;
        float4* sn = (float4*)swn;
        #pragma unroll
        for (int i = 0; i < DD*DD/4; i += 256) {
            float4 a = gp[i + tid];
            a.x *= alpha; a.y *= alpha; a.z *= alpha; a.w *= alpha;
            sp[i + tid] = a;
            float4 b = gn[i + tid];
            b.x *= beta; b.y *= beta; b.z *= beta; b.w *= beta;
            sn[i + tid] = b;
        }
    }
    __syncthreads();

    int n = blockIdx.x * 256 + tid;
    if (n >= NN) return;

    float ur[DD], vr[DD];
    const float4* uv4 = (const float4*)(uv + (size_t)n * 2*DD);
    #pragma unroll
    for (int i = 0; i < DD/4; ++i) {
        float4 a = uv4[i];
        ur[4*i+0] = a.x; ur[4*i+1] = a.y; ur[4*i+2] = a.z; ur[4*i+3] = a.w;
        float4 b = uv4[DD/4 + i];
        vr[4*i+0] = b.x; vr[4*i+1] = b.y; vr[4*i+2] = b.z; vr[4*i+3] = b.w;
    }

    float4* a4 = (float4*)(agg + (size_t)n * DD);
    for (int d0 = 0; d0 < DD; d0 += 4) {
        float4 acc = make_float4(0.f, 0.f, 0.f, 0.f);
        #pragma unroll
        for (int k = 0; k < DD; ++k) {
            float uk = ur[k], vk = vr[k];
            acc.x += uk * swp[(d0+0)*DD + k] + vk * swn[(d0+0)*DD + k];
            acc.y += uk * swp[(d0+1)*DD + k] + vk * swn[(d0+1)*DD + k];
            acc.z += uk * swp[(d0+2)*DD + k] + vk * swn[(d0+2)*DD + k];
            acc.w += uk * swp[(d0+3)*DD + k] + vk * swn[(d0+3)*DD + k];
        }
        a4[d0/4] = acc;
    }
}

// K5: thread-per-node fused epilogue with LDS-staged MLP weights.
__global__ __launch_bounds__(256) void k5_node(
    const float* __restrict__ agg, const float* __restrict__ x,
    const float* __restrict__ w1, const float* __restrict__ bb1,
    const float* __restrict__ w2T, const float* __restrict__ bb2,
    const float* __restrict__ g1, const float* __restrict__ be1,
    const float* __restrict__ g2, const float* __restrict__ be2,
    float* __restrict__ out)
{
    __shared__ float sw1[2*DD * DD];   // 32 KB
    __shared__ float sw2[2*DD * DD];   // 32 KB (transposed w2)
    __shared__ float sb1[2*DD];        // 512 B

    int tid = threadIdx.x;
    {
        const float4* gw1 = (const float4*)w1;
        const float4* gw2 = (const float4*)w2T;
        float4* s1p = (float4*)sw1;
        float4* s2p = (float4*)sw2;
        #pragma unroll
        for (int i = 0; i < 2*DD*DD/4; i += 256) { s1p[i + tid] = gw1[i + tid]; s2p[i + tid] = gw2[i + tid]; }
        if (tid < 2*DD/4) ((float4*)sb1)[tid] = ((const float4*)bb1)[tid];
    }
    __syncthreads();

    int n = blockIdx.x * 256 + tid;
    if (n >= NN) return;

    float h[DD];
    {
        const float4* a4 = (const float4*)(agg + (size_t)n * DD);
        const float4* x4 = (const float4*)(x   + (size_t)n * DD);
        #pragma unroll
        for (int i = 0; i < DD/4; ++i) {
            float4 av = a4[i];
            float4 xv = x4[i];
            h[4*i+0] = gelu_exact(av.x) + xv.x;
            h[4*i+1] = gelu_exact(av.y) + xv.y;
            h[4*i+2] = gelu_exact(av.z) + xv.z;
            h[4*i+3] = gelu_exact(av.w) + xv.w;
        }
        float mu = 0.f;
        #pragma unroll
        for (int d = 0; d < DD; ++d) mu += h[d];
        mu *= (1.0f/DD);
        float var = 0.f;
        #pragma unroll
        for (int d = 0; d < DD; ++d) { float t = h[d]-mu; var += t*t; }
        var *= (1.0f/DD);
        float rs = rsqrtf(var + 1e-5f);
        #pragma unroll
        for (int d = 0; d < DD; ++d) h[d] = (h[d]-mu)*rs*g1[d] + be1[d];
    }

    float m[DD];
    #pragma unroll
    for (int d = 0; d < DD; ++d) m[d] = 0.f;

    #pragma unroll 2
    for (int j = 0; j < 2*DD; ++j) {
        float t0=0.f,t1=0.f,t2=0.f,t3=0.f;
        #pragma unroll
        for (int k = 0; k < DD; k += 4) {
            float4 w = *(const float4*)&sw1[j*DD + k];
            t0 += h[k+0]*w.x; t1 += h[k+1]*w.y;
            t2 += h[k+2]*w.z; t3 += h[k+3]*w.w;
        }
        float g = gelu_exact((t0+t1)+(t2+t3) + sb1[j]);
        #pragma unroll
        for (int k = 0; k < DD; k += 4) {
            float4 w = *(const float4*)&sw2[j*DD + k];
            m[k+0] += g*w.x; m[k+1] += g*w.y;
            m[k+2] += g*w.z; m[k+3] += g*w.w;
        }
    }

    {
        #pragma unroll
        for (int d = 0; d < DD; ++d) m[d] += h[d] + bb2[d];
        float mu = 0.f;
        #pragma unroll
        for (int d = 0; d < DD; ++d) mu += m[d];
        mu *= (1.0f/DD);
        float var = 0.f;
        #pragma unroll
        for (int d = 0; d < DD; ++d) { float t = m[d]-mu; var += t*t; }
        var *= (1.0f/DD);
        float rs = rsqrtf(var + 1e-5f);
        float4* o4 = (float4*)(out + (size_t)n * DD);
        #pragma unroll
        for (int i = 0; i < DD/4; ++i) {
            float4 o;
            o.x = (m[4*i+0]-mu)*rs*g2[4*i+0] + be2[4*i+0];
            o.y = (m[4*i+1]-mu)*rs*g2[4*i+1] + be2[4*i+1];
            o.z = (m[4*i+2]-mu)*rs*g2[4*i+2] + be2[4*i+2];
            o.w = (m[4*i+3]-mu)*rs*g2[4*i+3] + be2[4*i+3];
            o4[i] = o;
        }
    }
}

extern "C" void kernel_launch(void* const* d_in, const int* in_sizes, int n_in,
                              void* d_out, int out_size, void* d_ws, size_t ws_size,
                              hipStream_t stream) {
    const float* x    = (const float*)d_in[0];
    const int*   ei   = (const int*)d_in[1];
    const float* rf   = (const float*)d_in[2];
    const float* Wp   = (const float*)d_in[3];
    const float* Wn   = (const float*)d_in[4];
    const float* attw = (const float*)d_in[5];
    const float* cf   = (const float*)d_in[6];
    const float* w1   = (const float*)d_in[7];
    const float* b1   = (const float*)d_in[8];
    const float* w2   = (const float*)d_in[9];
    const float* b2   = (const float*)d_in[10];
    const float* g1   = (const float*)d_in[11];
    const float* be1  = (const float*)d_in[12];
    const float* g2   = (const float*)d_in[13];
    const float* be2  = (const float*)d_in[14];
    float* out = (float*)d_out;

    float* ws = (float*)d_ws;
    float*  s1     = ws;                                  // NN
    float*  s2     = s1 + NN;                             // NN
    float*  uv     = s2 + NN;                             // NN*2*DD
    float*  agg    = uv + (size_t)NN * 2*DD;              // NN*DD
    float*  w2T    = agg + (size_t)NN * DD;               // 2*DD*DD
    float2* sorted = (float2*)(w2T + 2*DD*DD);            // NE float2
    int*    count  = (int*)(sorted + NE);                 // NN
    int*    off    = count + NN;                          // NN+1
    int*    pos    = off + NN + 1;                        // NN
    int*    bsum   = pos + NN;                            // 512

    hipMemsetAsync(count, 0, NN * sizeof(int), stream);

    k0_transpose<<<32, 256, 0, stream>>>(w2, w2T);
    k1_scores   <<<(NN+255)/256, 256, 0, stream>>>(x, attw, s1, s2);
    kh_hist     <<<NE/256, 256, 0, stream>>>(ei, count);
    ks_scanA    <<<NB, 256, 0, stream>>>(count, off, bsum);
    ks_scanB    <<<1, 512, 0, stream>>>(bsum);
    ks_scanC    <<<NB, 256, 0, stream>>>(off, pos, bsum);
    kscat       <<<NE/256, 256, 0, stream>>>(ei, rf, pos, sorted);
    k4a_agg     <<<NN/4, 256, 0, stream>>>(sorted, off, s1, s2, x, uv);
    k4b_mm      <<<(NN+255)/256, 256, 0, stream>>>(uv, Wp, Wn, cf, agg);
    k5_node     <<<(NN+255)/256, 256, 0, stream>>>(agg, x, w1, b1, w2T, b2, g1, be1, g2, be2, out);
}

// Round 5
// 707.022 us; speedup vs baseline: 1.5700x; 1.0683x over previous
//
#include <hip/hip_runtime.h>
#include <math.h>

#define NN 100000
#define NE 1600000
#define DD 64
#define NB ((NN + 255) / 256)   // 391 scan blocks

__device__ __forceinline__ float gelu_exact(float v) {
    return 0.5f * v * (1.0f + erff(v * 0.7071067811865475f));
}

__device__ __forceinline__ float wave_max64(float v) {
    #pragma unroll
    for (int o = 32; o > 0; o >>= 1) v = fmaxf(v, __shfl_xor(v, o));
    return v;
}
__device__ __forceinline__ float wave_sum64(float v) {
    #pragma unroll
    for (int o = 32; o > 0; o >>= 1) v += __shfl_xor(v, o);
    return v;
}

// K0: transpose w2[64][128] -> w2T[128][64] for k5
__global__ __launch_bounds__(256) void k0_transpose(
    const float* __restrict__ w2, float* __restrict__ w2T)
{
    int t = blockIdx.x * 256 + threadIdx.x;   // 8192
    int j = t & 127;
    int d = t >> 7;
    w2T[j * DD + d] = w2[d * 2 * DD + j];
}

// K1: per-node attention projections: s1 = x.att_w[:D], s2 = x.att_w[D:]
__global__ __launch_bounds__(256) void k1_scores(
    const float* __restrict__ x, const float* __restrict__ attw,
    float* __restrict__ s1, float* __restrict__ s2)
{
    int n = blockIdx.x * 256 + threadIdx.x;
    if (n >= NN) return;
    const float4* x4 = (const float4*)(x + (size_t)n * DD);
    float a = 0.f, b = 0.f;
    #pragma unroll
    for (int i = 0; i < DD/4; ++i) {
        float4 v = x4[i];
        a += v.x*attw[4*i+0] + v.y*attw[4*i+1] + v.z*attw[4*i+2] + v.w*attw[4*i+3];
        b += v.x*attw[DD+4*i+0] + v.y*attw[DD+4*i+1] + v.z*attw[DD+4*i+2] + v.w*attw[DD+4*i+3];
    }
    s1[n] = a;
    s2[n] = b;
}

// KH: histogram of dst
__global__ __launch_bounds__(256) void kh_hist(
    const int* __restrict__ ei, int* __restrict__ count)
{
    int e = blockIdx.x * 256 + threadIdx.x;
    if (e >= NE) return;
    atomicAdd(count + ei[NE + e], 1);
}

// KSA: per-block exclusive scan of count -> off (block-local), block totals -> bsum
__global__ __launch_bounds__(256) void ks_scanA(
    const int* __restrict__ cnt, int* __restrict__ off, int* __restrict__ bsum)
{
    __shared__ int sa[256], sb[256];
    int t = threadIdx.x;
    int i = blockIdx.x * 256 + t;
    int v = (i < NN) ? cnt[i] : 0;
    sa[t] = v;
    __syncthreads();
    int* s = sa; int* d = sb;
    #pragma unroll
    for (int o = 1; o < 256; o <<= 1) {
        d[t] = s[t] + ((t >= o) ? s[t - o] : 0);
        __syncthreads();
        int* tmp = s; s = d; d = tmp;
    }
    int incl = s[t];
    if (i < NN) off[i] = incl - v;
    if (t == 255) bsum[blockIdx.x] = incl;
}

// KSB: single-block exclusive scan of the NB block sums
__global__ __launch_bounds__(512) void ks_scanB(int* __restrict__ bsum)
{
    __shared__ int sa[512], sb[512];
    int t = threadIdx.x;
    int v = (t < NB) ? bsum[t] : 0;
    sa[t] = v;
    __syncthreads();
    int* s = sa; int* d = sb;
    #pragma unroll
    for (int o = 1; o < 512; o <<= 1) {
        d[t] = s[t] + ((t >= o) ? s[t - o] : 0);
        __syncthreads();
        int* tmp = s; s = d; d = tmp;
    }
    if (t < NB) bsum[t] = s[t] - v;   // exclusive
}

// KSC: add block bases; duplicate into pos; set sentinel off[NN]=NE
__global__ __launch_bounds__(256) void ks_scanC(
    int* __restrict__ off, int* __restrict__ pos, const int* __restrict__ bsum)
{
    int i = blockIdx.x * 256 + threadIdx.x;
    if (i < NN) {
        int o = off[i] + bsum[blockIdx.x];
        off[i] = o;
        pos[i] = o;
    }
    if (i == 0) off[NN] = NE;
}

// KSCAT: scatter edges into dst-sorted order as {src (bits), rf}
__global__ __launch_bounds__(256) void kscat(
    const int* __restrict__ ei, const float* __restrict__ rf,
    int* __restrict__ pos, float2* __restrict__ sorted)
{
    int e = blockIdx.x * 256 + threadIdx.x;
    if (e >= NE) return;
    int src = ei[e];
    int dst = ei[NE + e];
    int p = atomicAdd(pos + dst, 1);
    sorted[p] = make_float2(__int_as_float(src), rf[e]);
}

// K4A: wave-per-node fused softmax + aggregation.
// u = sum_e att*rf*x[src], v = sum_e att*x[src]  (lane = feature dim)
__global__ __launch_bounds__(256) void k4a_agg(
    const float2* __restrict__ sorted, const int* __restrict__ off,
    const float* __restrict__ s1, const float* __restrict__ s2,
    const float* __restrict__ x, float* __restrict__ uv)
{
    int lane = threadIdx.x & 63;
    int n = blockIdx.x * 4 + (threadIdx.x >> 6);   // grid = NN/4 blocks, always valid
    int r0 = off[n], r1 = off[n + 1];
    float s2n = s2[n];

    // online softmax: running max m, denom den
    float m = -INFINITY, den = 0.f;
    for (int base = r0; base < r1; base += 64) {
        int idx = base + lane;
        float sc = -INFINITY;
        if (idx < r1) {
            float2 p = sorted[idx];
            sc = s1[__float_as_int(p.x)] + s2n;
        }
        float cm = wave_max64(sc);
        float nm = fmaxf(m, cm);
        float term = (idx < r1) ? __expf(sc - nm) : 0.f;
        den = den * __expf(m - nm) + wave_sum64(term);
        m = nm;
    }

    // weighted accumulation, 4-way software-pipelined gathers
    float u = 0.f, v = 0.f;
    for (int base = r0; base < r1; base += 64) {
        int idx = base + lane;
        int cnt = min(64, r1 - base);
        int srcl = 0; float rfl = 0.f, el = 0.f;
        if (idx < r1) {
            float2 p = sorted[idx];
            srcl = __float_as_int(p.x);
            rfl = p.y;
            el = __expf(s1[srcl] + s2n - m);
        }
        int j = 0;
        for (; j + 4 <= cnt; j += 4) {
            int   a0 = __shfl(srcl, j+0), a1 = __shfl(srcl, j+1);
            int   a2 = __shfl(srcl, j+2), a3 = __shfl(srcl, j+3);
            float e0 = __shfl(el, j+0), e1 = __shfl(el, j+1);
            float e2 = __shfl(el, j+2), e3 = __shfl(el, j+3);
            float f0 = __shfl(rfl, j+0), f1 = __shfl(rfl, j+1);
            float f2 = __shfl(rfl, j+2), f3 = __shfl(rfl, j+3);
            float x0 = x[(size_t)a0 * DD + lane];
            float x1 = x[(size_t)a1 * DD + lane];
            float x2 = x[(size_t)a2 * DD + lane];
            float x3 = x[(size_t)a3 * DD + lane];
            v += e0*x0 + e1*x1 + e2*x2 + e3*x3;
            u += e0*f0*x0 + e1*f1*x1 + e2*f2*x2 + e3*f3*x3;
        }
        for (; j < cnt; ++j) {
            int   sj = __shfl(srcl, j);
            float ej = __shfl(el,   j);
            float fj = __shfl(rfl,  j);
            float xv = x[(size_t)sj * DD + lane];
            v += ej * xv;
            u += ej * fj * xv;
        }
    }
    float inv = (r1 > r0) ? 1.f / den : 0.f;
    uv[(size_t)n * 2*DD + lane]      = u * inv;
    uv[(size_t)n * 2*DD + DD + lane] = v * inv;
}

// K4B: thread-per-node matmul: agg = alpha*u@Wp^T + (1-alpha)*v@Wn^T
__global__ __launch_bounds__(256) void k4b_mm(
    const float* __restrict__ uv, const float* __restrict__ Wp,
    const float* __restrict__ Wn, const float* __restrict__ cf,
    float* __restrict__ agg)
{
    __shared__ float swp[DD * DD];   // 16 KB, alpha-scaled
    __shared__ float swn[DD * DD];   // 16 KB, beta-scaled

    int tid = threadIdx.x;
    float alpha = 1.0f / (1.0f + __expf(-cf[0]));
    float beta  = 1.0f - alpha;
    {
        const float4* gp = (const float4*)Wp;
        const float4* gn = (const float4*)Wn;
        float4* sp = (float4*)swp;
        float4* sn = (float4*)swn;
        #pragma unroll
        for (int i = 0; i < DD*DD/4; i += 256) {
            float4 a = gp[i + tid];
            a.x *= alpha; a.y *= alpha; a.z *= alpha; a.w *= alpha;
            sp[i + tid] = a;
            float4 b = gn[i + tid];
            b.x *= beta; b.y *= beta; b.z *= beta; b.w *= beta;
            sn[i + tid] = b;
        }
    }
    __syncthreads();

    int n = blockIdx.x * 256 + tid;
    if (n >= NN) return;

    float ur[DD], vr[DD];
    const float4* uv4 = (const float4*)(uv + (size_t)n * 2*DD);
    #pragma unroll
    for (int i = 0; i < DD/4; ++i) {
        float4 a = uv4[i];
        ur[4*i+0] = a.x; ur[4*i+1] = a.y; ur[4*i+2] = a.z; ur[4*i+3] = a.w;
        float4 b = uv4[DD/4 + i];
        vr[4*i+0] = b.x; vr[4*i+1] = b.y; vr[4*i+2] = b.z; vr[4*i+3] = b.w;
    }

    float4* a4 = (float4*)(agg + (size_t)n * DD);
    for (int d0 = 0; d0 < DD; d0 += 4) {
        float4 acc = make_float4(0.f, 0.f, 0.f, 0.f);
        #pragma unroll
        for (int k = 0; k < DD; ++k) {
            float uk = ur[k], vk = vr[k];
            acc.x += uk * swp[(d0+0)*DD + k] + vk * swn[(d0+0)*DD + k];
            acc.y += uk * swp[(d0+1)*DD + k] + vk * swn[(d0+1)*DD + k];
            acc.z += uk * swp[(d0+2)*DD + k] + vk * swn[(d0+2)*DD + k];
            acc.w += uk * swp[(d0+3)*DD + k] + vk * swn[(d0+3)*DD + k];
        }
        a4[d0/4] = acc;
    }
}

// K5: wave-split fused epilogue. Block = 64 nodes x 4 waves; LDS-staged weights
// (broadcast reads); wave q does MLP hidden slice j in [32q,32q+32); partial m
// exchanged through LDS (aliased over the dead weight buffers); wave 0 finishes.
__global__ __launch_bounds__(256) void k5_node(
    const float* __restrict__ agg, const float* __restrict__ x,
    const float* __restrict__ w1, const float* __restrict__ bb1,
    const float* __restrict__ w2T, const float* __restrict__ bb2,
    const float* __restrict__ g1, const float* __restrict__ be1,
    const float* __restrict__ g2, const float* __restrict__ be2,
    float* __restrict__ out)
{
    __shared__ float smem[4*DD*DD + 2*DD];   // 64.5 KB -> 2 blocks/CU
    float* sw1 = smem;                // w1 [128][64]
    float* sw2 = smem + 2*DD*DD;      // w2T [128][64]
    float* sb1 = smem + 4*DD*DD;      // b1 [128]
    float* part = smem;               // ALIAS: partials 3*64*65 floats (after barrier)

    int tid = threadIdx.x;
    {
        const float4* gw1 = (const float4*)w1;
        const float4* gw2 = (const float4*)w2T;
        #pragma unroll
        for (int i = 0; i < 2*DD*DD/4; i += 256) {
            ((float4*)sw1)[i + tid] = gw1[i + tid];
            ((float4*)sw2)[i + tid] = gw2[i + tid];
        }
        if (tid < 2*DD/4) ((float4*)sb1)[tid] = ((const float4*)bb1)[tid];
    }
    __syncthreads();

    int lane = tid & 63;
    int q    = tid >> 6;              // wave id, uniform
    int n    = blockIdx.x * 64 + lane;
    bool ok  = (n < NN);

    float h[DD];
    if (ok) {
        const float4* a4 = (const float4*)(agg + (size_t)n * DD);
        const float4* x4 = (const float4*)(x   + (size_t)n * DD);
        #pragma unroll
        for (int i = 0; i < DD/4; ++i) {
            float4 av = a4[i];
            float4 xv = x4[i];
            h[4*i+0] = gelu_exact(av.x) + xv.x;
            h[4*i+1] = gelu_exact(av.y) + xv.y;
            h[4*i+2] = gelu_exact(av.z) + xv.z;
            h[4*i+3] = gelu_exact(av.w) + xv.w;
        }
        float mu = 0.f;
        #pragma unroll
        for (int d = 0; d < DD; ++d) mu += h[d];
        mu *= (1.0f/DD);
        float var = 0.f;
        #pragma unroll
        for (int d = 0; d < DD; ++d) { float t = h[d]-mu; var += t*t; }
        var *= (1.0f/DD);
        float rs = rsqrtf(var + 1e-5f);
        #pragma unroll
        for (int d = 0; d < DD; ++d) h[d] = (h[d]-mu)*rs*g1[d] + be1[d];
    } else {
        #pragma unroll
        for (int d = 0; d < DD; ++d) h[d] = 0.f;
    }

    // MLP j-slice [32q, 32q+32)
    float m[DD];
    #pragma unroll
    for (int d = 0; d < DD; ++d) m[d] = 0.f;
    int j0 = q * 32;
    for (int jj = 0; jj < 32; ++jj) {
        int j = j0 + jj;
        float t0=0.f,t1=0.f,t2=0.f,t3=0.f;
        #pragma unroll
        for (int k = 0; k < DD; k += 4) {
            float4 w = *(const float4*)&sw1[j*DD + k];
            t0 += h[k+0]*w.x; t1 += h[k+1]*w.y;
            t2 += h[k+2]*w.z; t3 += h[k+3]*w.w;
        }
        float g = gelu_exact((t0+t1)+(t2+t3) + sb1[j]);
        #pragma unroll
        for (int k = 0; k < DD; k += 4) {
            float4 w = *(const float4*)&sw2[j*DD + k];
            m[k+0] += g*w.x; m[k+1] += g*w.y;
            m[k+2] += g*w.z; m[k+3] += g*w.w;
        }
    }

    __syncthreads();   // everyone done reading weights; LDS reusable
    if (q > 0) {
        float* p = part + ((size_t)(q-1)*64 + lane) * 65;   // stride 65: conflict-free
        #pragma unroll
        for (int d = 0; d < DD; ++d) p[d] = m[d];
    }
    __syncthreads();

    if (q == 0) {
        #pragma unroll
        for (int qq = 0; qq < 3; ++qq) {
            const float* p = part + ((size_t)qq*64 + lane) * 65;
            #pragma unroll
            for (int d = 0; d < DD; ++d) m[d] += p[d];
        }
        #pragma unroll
        for (int d = 0; d < DD; ++d) m[d] += h[d] + bb2[d];
        float mu = 0.f;
        #pragma unroll
        for (int d = 0; d < DD; ++d) mu += m[d];
        mu *= (1.0f/DD);
        float var = 0.f;
        #pragma unroll
        for (int d = 0; d < DD; ++d) { float t = m[d]-mu; var += t*t; }
        var *= (1.0f/DD);
        float rs = rsqrtf(var + 1e-5f);
        if (ok) {
            float4* o4 = (float4*)(out + (size_t)n * DD);
            #pragma unroll
            for (int i = 0; i < DD/4; ++i) {
                float4 o;
                o.x = (m[4*i+0]-mu)*rs*g2[4*i+0] + be2[4*i+0];
                o.y = (m[4*i+1]-mu)*rs*g2[4*i+1] + be2[4*i+1];
                o.z = (m[4*i+2]-mu)*rs*g2[4*i+2] + be2[4*i+2];
                o.w = (m[4*i+3]-mu)*rs*g2[4*i+3] + be2[4*i+3];
                o4[i] = o;
            }
        }
    }
}

extern "C" void kernel_launch(void* const* d_in, const int* in_sizes, int n_in,
                              void* d_out, int out_size, void* d_ws, size_t ws_size,
                              hipStream_t stream) {
    const float* x    = (const float*)d_in[0];
    const int*   ei   = (const int*)d_in[1];
    const float* rf   = (const float*)d_in[2];
    const float* Wp   = (const float*)d_in[3];
    const float* Wn   = (const float*)d_in[4];
    const float* attw = (const float*)d_in[5];
    const float* cf   = (const float*)d_in[6];
    const float* w1   = (const float*)d_in[7];
    const float* b1   = (const float*)d_in[8];
    const float* w2   = (const float*)d_in[9];
    const float* b2   = (const float*)d_in[10];
    const float* g1   = (const float*)d_in[11];
    const float* be1  = (const float*)d_in[12];
    const float* g2   = (const float*)d_in[13];
    const float* be2  = (const float*)d_in[14];
    float* out = (float*)d_out;

    float* ws = (float*)d_ws;
    float*  s1     = ws;                                  // NN
    float*  s2     = s1 + NN;                             // NN
    float*  uv     = s2 + NN;                             // NN*2*DD
    float*  agg    = uv + (size_t)NN * 2*DD;              // NN*DD
    float*  w2T    = agg + (size_t)NN * DD;               // 2*DD*DD
    float2* sorted = (float2*)(w2T + 2*DD*DD);            // NE float2
    int*    count  = (int*)(sorted + NE);                 // NN
    int*    off    = count + NN;                          // NN+1
    int*    pos    = off + NN + 1;                        // NN
    int*    bsum   = pos + NN;                            // 512

    hipMemsetAsync(count, 0, NN * sizeof(int), stream);

    k0_transpose<<<32, 256, 0, stream>>>(w2, w2T);
    k1_scores   <<<(NN+255)/256, 256, 0, stream>>>(x, attw, s1, s2);
    kh_hist     <<<NE/256, 256, 0, stream>>>(ei, count);
    ks_scanA    <<<NB, 256, 0, stream>>>(count, off, bsum);
    ks_scanB    <<<1, 512, 0, stream>>>(bsum);
    ks_scanC    <<<NB, 256, 0, stream>>>(off, pos, bsum);
    kscat       <<<NE/256, 256, 0, stream>>>(ei, rf, pos, sorted);
    k4a_agg     <<<NN/4, 256, 0, stream>>>(sorted, off, s1, s2, x, uv);
    k4b_mm      <<<(NN+255)/256, 256, 0, stream>>>(uv, Wp, Wn, cf, agg);
    k5_node     <<<(NN+63)/64, 256, 0, stream>>>(agg, x, w1, b1, w2T, b2, g1, be1, g2, be2, out);
}

// Round 6
// 667.680 us; speedup vs baseline: 1.6625x; 1.0589x over previous
//
#include <hip/hip_runtime.h>
#include <math.h>

#define NN 100000
#define NE 1600000
#define DD 64
#define NB ((NN + 255) / 256)   // 391 scan blocks

__device__ __forceinline__ float gelu_exact(float v) {
    return 0.5f * v * (1.0f + erff(v * 0.7071067811865475f));
}

__device__ __forceinline__ float wave_max64(float v) {
    #pragma unroll
    for (int o = 32; o > 0; o >>= 1) v = fmaxf(v, __shfl_xor(v, o));
    return v;
}
__device__ __forceinline__ float wave_sum64(float v) {
    #pragma unroll
    for (int o = 32; o > 0; o >>= 1) v += __shfl_xor(v, o);
    return v;
}

// K0: transpose w2[64][128] -> w2T[128][64]
__global__ __launch_bounds__(256) void k0_transpose(
    const float* __restrict__ w2, float* __restrict__ w2T)
{
    int t = blockIdx.x * 256 + threadIdx.x;   // 8192
    int j = t & 127;
    int d = t >> 7;
    w2T[j * DD + d] = w2[d * 2 * DD + j];
}

// K1: per-node attention projections: s1 = x.att_w[:D], s2 = x.att_w[D:]
__global__ __launch_bounds__(256) void k1_scores(
    const float* __restrict__ x, const float* __restrict__ attw,
    float* __restrict__ s1, float* __restrict__ s2)
{
    int n = blockIdx.x * 256 + threadIdx.x;
    if (n >= NN) return;
    const float4* x4 = (const float4*)(x + (size_t)n * DD);
    float a = 0.f, b = 0.f;
    #pragma unroll
    for (int i = 0; i < DD/4; ++i) {
        float4 v = x4[i];
        a += v.x*attw[4*i+0] + v.y*attw[4*i+1] + v.z*attw[4*i+2] + v.w*attw[4*i+3];
        b += v.x*attw[DD+4*i+0] + v.y*attw[DD+4*i+1] + v.z*attw[DD+4*i+2] + v.w*attw[DD+4*i+3];
    }
    s1[n] = a;
    s2[n] = b;
}

// KH: histogram of dst
__global__ __launch_bounds__(256) void kh_hist(
    const int* __restrict__ ei, int* __restrict__ count)
{
    int e = blockIdx.x * 256 + threadIdx.x;
    if (e >= NE) return;
    atomicAdd(count + ei[NE + e], 1);
}

// KSA: per-block exclusive scan of count -> off (block-local), block totals -> bsum
__global__ __launch_bounds__(256) void ks_scanA(
    const int* __restrict__ cnt, int* __restrict__ off, int* __restrict__ bsum)
{
    __shared__ int sa[256], sb[256];
    int t = threadIdx.x;
    int i = blockIdx.x * 256 + t;
    int v = (i < NN) ? cnt[i] : 0;
    sa[t] = v;
    __syncthreads();
    int* s = sa; int* d = sb;
    #pragma unroll
    for (int o = 1; o < 256; o <<= 1) {
        d[t] = s[t] + ((t >= o) ? s[t - o] : 0);
        __syncthreads();
        int* tmp = s; s = d; d = tmp;
    }
    int incl = s[t];
    if (i < NN) off[i] = incl - v;
    if (t == 255) bsum[blockIdx.x] = incl;
}

// KSB: single-block exclusive scan of the NB block sums
__global__ __launch_bounds__(512) void ks_scanB(int* __restrict__ bsum)
{
    __shared__ int sa[512], sb[512];
    int t = threadIdx.x;
    int v = (t < NB) ? bsum[t] : 0;
    sa[t] = v;
    __syncthreads();
    int* s = sa; int* d = sb;
    #pragma unroll
    for (int o = 1; o < 512; o <<= 1) {
        d[t] = s[t] + ((t >= o) ? s[t - o] : 0);
        __syncthreads();
        int* tmp = s; s = d; d = tmp;
    }
    if (t < NB) bsum[t] = s[t] - v;   // exclusive
}

// KSC: add block bases; duplicate into pos; set sentinel off[NN]=NE
__global__ __launch_bounds__(256) void ks_scanC(
    int* __restrict__ off, int* __restrict__ pos, const int* __restrict__ bsum)
{
    int i = blockIdx.x * 256 + threadIdx.x;
    if (i < NN) {
        int o = off[i] + bsum[blockIdx.x];
        off[i] = o;
        pos[i] = o;
    }
    if (i == 0) off[NN] = NE;
}

// KSCAT: scatter edges into dst-sorted order as {src (bits), rf}
__global__ __launch_bounds__(256) void kscat(
    const int* __restrict__ ei, const float* __restrict__ rf,
    int* __restrict__ pos, float2* __restrict__ sorted)
{
    int e = blockIdx.x * 256 + threadIdx.x;
    if (e >= NE) return;
    int src = ei[e];
    int dst = ei[NE + e];
    int p = atomicAdd(pos + dst, 1);
    sorted[p] = make_float2(__int_as_float(src), rf[e]);
}

// K4A: wave-per-node fused softmax + aggregation.
__global__ __launch_bounds__(256) void k4a_agg(
    const float2* __restrict__ sorted, const int* __restrict__ off,
    const float* __restrict__ s1, const float* __restrict__ s2,
    const float* __restrict__ x, float* __restrict__ uv)
{
    int lane = threadIdx.x & 63;
    int n = blockIdx.x * 4 + (threadIdx.x >> 6);
    int r0 = off[n], r1 = off[n + 1];
    float s2n = s2[n];

    float m = -INFINITY, den = 0.f;
    for (int base = r0; base < r1; base += 64) {
        int idx = base + lane;
        float sc = -INFINITY;
        if (idx < r1) {
            float2 p = sorted[idx];
            sc = s1[__float_as_int(p.x)] + s2n;
        }
        float cm = wave_max64(sc);
        float nm = fmaxf(m, cm);
        float term = (idx < r1) ? __expf(sc - nm) : 0.f;
        den = den * __expf(m - nm) + wave_sum64(term);
        m = nm;
    }

    float u = 0.f, v = 0.f;
    for (int base = r0; base < r1; base += 64) {
        int idx = base + lane;
        int cnt = min(64, r1 - base);
        int srcl = 0; float rfl = 0.f, el = 0.f;
        if (idx < r1) {
            float2 p = sorted[idx];
            srcl = __float_as_int(p.x);
            rfl = p.y;
            el = __expf(s1[srcl] + s2n - m);
        }
        int j = 0;
        for (; j + 4 <= cnt; j += 4) {
            int   a0 = __shfl(srcl, j+0), a1 = __shfl(srcl, j+1);
            int   a2 = __shfl(srcl, j+2), a3 = __shfl(srcl, j+3);
            float e0 = __shfl(el, j+0), e1 = __shfl(el, j+1);
            float e2 = __shfl(el, j+2), e3 = __shfl(el, j+3);
            float f0 = __shfl(rfl, j+0), f1 = __shfl(rfl, j+1);
            float f2 = __shfl(rfl, j+2), f3 = __shfl(rfl, j+3);
            float x0 = x[(size_t)a0 * DD + lane];
            float x1 = x[(size_t)a1 * DD + lane];
            float x2 = x[(size_t)a2 * DD + lane];
            float x3 = x[(size_t)a3 * DD + lane];
            v += e0*x0 + e1*x1 + e2*x2 + e3*x3;
            u += e0*f0*x0 + e1*f1*x1 + e2*f2*x2 + e3*f3*x3;
        }
        for (; j < cnt; ++j) {
            int   sj = __shfl(srcl, j);
            float ej = __shfl(el,   j);
            float fj = __shfl(rfl,  j);
            float xv = x[(size_t)sj * DD + lane];
            v += ej * xv;
            u += ej * fj * xv;
        }
    }
    float inv = (r1 > r0) ? 1.f / den : 0.f;
    uv[(size_t)n * 2*DD + lane]      = u * inv;
    uv[(size_t)n * 2*DD + DD + lane] = v * inv;
}

// K4B: thread-per-node matmul: agg = alpha*u@Wp^T + (1-alpha)*v@Wn^T
__global__ __launch_bounds__(256) void k4b_mm(
    const float* __restrict__ uv, const float* __restrict__ Wp,
    const float* __restrict__ Wn, const float* __restrict__ cf,
    float* __restrict__ agg)
{
    __shared__ float swp[DD * DD];   // 16 KB, alpha-scaled
    __shared__ float swn[DD * DD];   // 16 KB, beta-scaled

    int tid = threadIdx.x;
    float alpha = 1.0f / (1.0f + __expf(-cf[0]));
    float beta  = 1.0f - alpha;
    {
        const float4* gp = (const float4*)Wp;
        const float4* gn = (const float4*)Wn;
        float4* sp = (float4*)swp;
        float4* sn = (float4*)swn;
        #pragma unroll
        for (int i = 0; i < DD*DD/4; i += 256) {
            float4 a = gp[i + tid];
            a.x *= alpha; a.y *= alpha; a.z *= alpha; a.w *= alpha;
            sp[i + tid] = a;
            float4 b = gn[i + tid];
            b.x *= beta; b.y *= beta; b.z *= beta; b.w *= beta;
            sn[i + tid] = b;
        }
    }
    __syncthreads();

    int n = blockIdx.x * 256 + tid;
    if (n >= NN) return;

    float ur[DD], vr[DD];
    const float4* uv4 = (const float4*)(uv + (size_t)n * 2*DD);
    #pragma unroll
    for (int i = 0; i < DD/4; ++i) {
        float4 a = uv4[i];
        ur[4*i+0] = a.x; ur[4*i+1] = a.y; ur[4*i+2] = a.z; ur[4*i+3] = a.w;
        float4 b = uv4[DD/4 + i];
        vr[4*i+0] = b.x; vr[4*i+1] = b.y; vr[4*i+2] = b.z; vr[4*i+3] = b.w;
    }

    float4* a4 = (float4*)(agg + (size_t)n * DD);
    for (int d0 = 0; d0 < DD; d0 += 4) {
        float4 acc = make_float4(0.f, 0.f, 0.f, 0.f);
        #pragma unroll
        for (int k = 0; k < DD; ++k) {
            float uk = ur[k], vk = vr[k];
            acc.x += uk * swp[(d0+0)*DD + k] + vk * swn[(d0+0)*DD + k];
            acc.y += uk * swp[(d0+1)*DD + k] + vk * swn[(d0+1)*DD + k];
            acc.z += uk * swp[(d0+2)*DD + k] + vk * swn[(d0+2)*DD + k];
            acc.w += uk * swp[(d0+3)*DD + k] + vk * swn[(d0+3)*DD + k];
        }
        a4[d0/4] = acc;
    }
}

// K5A: h = LN1(gelu(agg)+x); store h; G[j][n] = gelu(h@w1^T + b1)  (transposed)
// Block = 128 threads (2 waves x 64 nodes, full j range). LDS = w1 only (32 KB).
__global__ __launch_bounds__(128) void k5a_mlp1(
    const float* __restrict__ agg, const float* __restrict__ x,
    const float* __restrict__ w1, const float* __restrict__ bb1,
    const float* __restrict__ g1, const float* __restrict__ be1,
    float* __restrict__ hout, float* __restrict__ G)
{
    __shared__ float sw1[2*DD * DD];   // 32 KB
    __shared__ float sb1[2*DD];        // 512 B

    int tid = threadIdx.x;
    {
        const float4* gw1 = (const float4*)w1;
        #pragma unroll
        for (int i = 0; i < 2*DD*DD/4; i += 128) ((float4*)sw1)[i + tid] = gw1[i + tid];
        if (tid < 2*DD/4) ((float4*)sb1)[tid] = ((const float4*)bb1)[tid];
    }
    __syncthreads();

    int n = blockIdx.x * 128 + tid;
    bool ok = (n < NN);

    float h[DD];
    if (ok) {
        const float4* a4 = (const float4*)(agg + (size_t)n * DD);
        const float4* x4 = (const float4*)(x   + (size_t)n * DD);
        #pragma unroll
        for (int i = 0; i < DD/4; ++i) {
            float4 av = a4[i];
            float4 xv = x4[i];
            h[4*i+0] = gelu_exact(av.x) + xv.x;
            h[4*i+1] = gelu_exact(av.y) + xv.y;
            h[4*i+2] = gelu_exact(av.z) + xv.z;
            h[4*i+3] = gelu_exact(av.w) + xv.w;
        }
        float mu = 0.f;
        #pragma unroll
        for (int d = 0; d < DD; ++d) mu += h[d];
        mu *= (1.0f/DD);
        float var = 0.f;
        #pragma unroll
        for (int d = 0; d < DD; ++d) { float t = h[d]-mu; var += t*t; }
        var *= (1.0f/DD);
        float rs = rsqrtf(var + 1e-5f);
        #pragma unroll
        for (int d = 0; d < DD; ++d) h[d] = (h[d]-mu)*rs*g1[d] + be1[d];
        float4* h4 = (float4*)(hout + (size_t)n * DD);
        #pragma unroll
        for (int i = 0; i < DD/4; ++i)
            h4[i] = make_float4(h[4*i+0], h[4*i+1], h[4*i+2], h[4*i+3]);
    } else {
        #pragma unroll
        for (int d = 0; d < DD; ++d) h[d] = 0.f;
    }

    #pragma unroll 2
    for (int j = 0; j < 2*DD; ++j) {
        float t0=0.f,t1=0.f,t2=0.f,t3=0.f;
        #pragma unroll
        for (int k = 0; k < DD; k += 4) {
            float4 w = *(const float4*)&sw1[j*DD + k];
            t0 += h[k+0]*w.x; t1 += h[k+1]*w.y;
            t2 += h[k+2]*w.z; t3 += h[k+3]*w.w;
        }
        float g = gelu_exact((t0+t1)+(t2+t3) + sb1[j]);
        if (ok) G[(size_t)j * NN + n] = g;   // coalesced across lanes
    }
}

// K5B: m = G[:,n]@w2T + b2 + h; out = LN2(m). LDS = w2T only (32 KB).
__global__ __launch_bounds__(128) void k5b_mlp2(
    const float* __restrict__ G, const float* __restrict__ hbuf,
    const float* __restrict__ w2T, const float* __restrict__ bb2,
    const float* __restrict__ g2, const float* __restrict__ be2,
    float* __restrict__ out)
{
    __shared__ float sw2[2*DD * DD];   // 32 KB

    int tid = threadIdx.x;
    {
        const float4* gw2 = (const float4*)w2T;
        #pragma unroll
        for (int i = 0; i < 2*DD*DD/4; i += 128) ((float4*)sw2)[i + tid] = gw2[i + tid];
    }
    __syncthreads();

    int n = blockIdx.x * 128 + tid;
    bool ok = (n < NN);

    float m[DD];
    #pragma unroll
    for (int d = 0; d < DD; ++d) m[d] = 0.f;

    // rolling prefetch of the coalesced G column
    float gcur = ok ? G[n] : 0.f;
    #pragma unroll 2
    for (int j = 0; j < 2*DD; ++j) {
        float gnext = (ok && j + 1 < 2*DD) ? G[(size_t)(j+1) * NN + n] : 0.f;
        #pragma unroll
        for (int k = 0; k < DD; k += 4) {
            float4 w = *(const float4*)&sw2[j*DD + k];
            m[k+0] += gcur*w.x; m[k+1] += gcur*w.y;
            m[k+2] += gcur*w.z; m[k+3] += gcur*w.w;
        }
        gcur = gnext;
    }

    if (!ok) return;
    // residual + bias + LN2
    float h[DD];
    const float4* h4 = (const float4*)(hbuf + (size_t)n * DD);
    #pragma unroll
    for (int i = 0; i < DD/4; ++i) {
        float4 v = h4[i];
        h[4*i+0] = v.x; h[4*i+1] = v.y; h[4*i+2] = v.z; h[4*i+3] = v.w;
    }
    #pragma unroll
    for (int d = 0; d < DD; ++d) m[d] += h[d] + bb2[d];
    float mu = 0.f;
    #pragma unroll
    for (int d = 0; d < DD; ++d) mu += m[d];
    mu *= (1.0f/DD);
    float var = 0.f;
    #pragma unroll
    for (int d = 0; d < DD; ++d) { float t = m[d]-mu; var += t*t; }
    var *= (1.0f/DD);
    float rs = rsqrtf(var + 1e-5f);
    float4* o4 = (float4*)(out + (size_t)n * DD);
    #pragma unroll
    for (int i = 0; i < DD/4; ++i) {
        float4 o;
        o.x = (m[4*i+0]-mu)*rs*g2[4*i+0] + be2[4*i+0];
        o.y = (m[4*i+1]-mu)*rs*g2[4*i+1] + be2[4*i+1];
        o.z = (m[4*i+2]-mu)*rs*g2[4*i+2] + be2[4*i+2];
        o.w = (m[4*i+3]-mu)*rs*g2[4*i+3] + be2[4*i+3];
        o4[i] = o;
    }
}

extern "C" void kernel_launch(void* const* d_in, const int* in_sizes, int n_in,
                              void* d_out, int out_size, void* d_ws, size_t ws_size,
                              hipStream_t stream) {
    const float* x    = (const float*)d_in[0];
    const int*   ei   = (const int*)d_in[1];
    const float* rf   = (const float*)d_in[2];
    const float* Wp   = (const float*)d_in[3];
    const float* Wn   = (const float*)d_in[4];
    const float* attw = (const float*)d_in[5];
    const float* cf   = (const float*)d_in[6];
    const float* w1   = (const float*)d_in[7];
    const float* b1   = (const float*)d_in[8];
    const float* w2   = (const float*)d_in[9];
    const float* b2   = (const float*)d_in[10];
    const float* g1   = (const float*)d_in[11];
    const float* be1  = (const float*)d_in[12];
    const float* g2   = (const float*)d_in[13];
    const float* be2  = (const float*)d_in[14];
    float* out = (float*)d_out;

    float* ws = (float*)d_ws;
    float*  s1     = ws;                                  // NN
    float*  s2     = s1 + NN;                             // NN
    float*  uv     = s2 + NN;                             // NN*2*DD  (aliased by G later)
    float*  agg    = uv + (size_t)NN * 2*DD;              // NN*DD
    float*  w2T    = agg + (size_t)NN * DD;               // 2*DD*DD
    float2* sorted = (float2*)(w2T + 2*DD*DD);            // NE float2
    int*    count  = (int*)(sorted + NE);                 // NN
    int*    off    = count + NN;                          // NN+1
    int*    pos    = off + NN + 1;                        // NN
    int*    bsum   = pos + NN;                            // 512
    float*  hbuf   = (float*)(bsum + 512);                // NN*DD
    float*  G      = uv;                                  // alias: uv dead after k4b

    hipMemsetAsync(count, 0, NN * sizeof(int), stream);

    k0_transpose<<<32, 256, 0, stream>>>(w2, w2T);
    k1_scores   <<<(NN+255)/256, 256, 0, stream>>>(x, attw, s1, s2);
    kh_hist     <<<NE/256, 256, 0, stream>>>(ei, count);
    ks_scanA    <<<NB, 256, 0, stream>>>(count, off, bsum);
    ks_scanB    <<<1, 512, 0, stream>>>(bsum);
    ks_scanC    <<<NB, 256, 0, stream>>>(off, pos, bsum);
    kscat       <<<NE/256, 256, 0, stream>>>(ei, rf, pos, sorted);
    k4a_agg     <<<NN/4, 256, 0, stream>>>(sorted, off, s1, s2, x, uv);
    k4b_mm      <<<(NN+255)/256, 256, 0, stream>>>(uv, Wp, Wn, cf, agg);
    k5a_mlp1    <<<(NN+127)/128, 128, 0, stream>>>(agg, x, w1, b1, g1, be1, hbuf, G);
    k5b_mlp2    <<<(NN+127)/128, 128, 0, stream>>>(G, hbuf, w2T, b2, g2, be2, out);
}

// Round 7
// 552.499 us; speedup vs baseline: 2.0091x; 1.2085x over previous
//
#include <hip/hip_runtime.h>
#include <math.h>

#define NN 100000
#define NE 1600000
#define DD 64
#define NB ((NN + 255) / 256)   // 391 scan blocks

typedef __attribute__((ext_vector_type(8))) short short8;
typedef __attribute__((ext_vector_type(4))) float f32x4;

__device__ __forceinline__ float gelu_exact(float v) {
    return 0.5f * v * (1.0f + erff(v * 0.7071067811865475f));
}

__device__ __forceinline__ unsigned short f2bf(float f) {   // RNE
    unsigned u = __float_as_uint(f);
    return (unsigned short)((u + 0x7FFFu + ((u >> 16) & 1u)) >> 16);
}
__device__ __forceinline__ float bf2f(unsigned short h) {
    return __uint_as_float((unsigned)h << 16);
}
__device__ __forceinline__ void split8(const float* a, short8& hi, short8& lo) {
    float4 x0 = *(const float4*)a;
    float4 x1 = *(const float4*)(a + 4);
    float v[8] = {x0.x, x0.y, x0.z, x0.w, x1.x, x1.y, x1.z, x1.w};
    #pragma unroll
    for (int i = 0; i < 8; ++i) {
        unsigned short h = f2bf(v[i]);
        hi[i] = (short)h;
        lo[i] = (short)f2bf(v[i] - bf2f(h));
    }
}

__device__ __forceinline__ float wave_max64(float v) {
    #pragma unroll
    for (int o = 32; o > 0; o >>= 1) v = fmaxf(v, __shfl_xor(v, o));
    return v;
}
__device__ __forceinline__ float wave_sum64(float v) {
    #pragma unroll
    for (int o = 32; o > 0; o >>= 1) v += __shfl_xor(v, o);
    return v;
}

// K0P: build bf16 hi/lo split weight buffers:
//   [0,8192)      Bmix[d][kk]: kk<64 -> alpha*Wp[d][kk], else beta*Wn[d][kk-64]
//   [8192,16384)  w1 linear   [j][k]  (B for h@w1^T)
//   [16384,24576) w2 linear   [d][j]  (B for G@w2^T)
__global__ __launch_bounds__(256) void k0prep(
    const float* __restrict__ Wp, const float* __restrict__ Wn,
    const float* __restrict__ w1, const float* __restrict__ w2,
    const float* __restrict__ cf,
    unsigned short* __restrict__ wh, unsigned short* __restrict__ wl)
{
    int t = blockIdx.x * 256 + threadIdx.x;   // 24576 total
    float alpha = 1.0f / (1.0f + __expf(-cf[0]));
    float beta  = 1.0f - alpha;
    float v;
    if (t < 8192) {
        int d = t >> 7, k = t & 127;
        v = (k < 64) ? alpha * Wp[d * 64 + k] : beta * Wn[d * 64 + (k - 64)];
    } else if (t < 16384) {
        v = w1[t - 8192];
    } else {
        v = w2[t - 16384];
    }
    unsigned short h = f2bf(v);
    wh[t] = h;
    wl[t] = f2bf(v - bf2f(h));
}

// K1: per-node attention projections: s1 = x.att_w[:D], s2 = x.att_w[D:]
__global__ __launch_bounds__(256) void k1_scores(
    const float* __restrict__ x, const float* __restrict__ attw,
    float* __restrict__ s1, float* __restrict__ s2)
{
    int n = blockIdx.x * 256 + threadIdx.x;
    if (n >= NN) return;
    const float4* x4 = (const float4*)(x + (size_t)n * DD);
    float a = 0.f, b = 0.f;
    #pragma unroll
    for (int i = 0; i < DD/4; ++i) {
        float4 v = x4[i];
        a += v.x*attw[4*i+0] + v.y*attw[4*i+1] + v.z*attw[4*i+2] + v.w*attw[4*i+3];
        b += v.x*attw[DD+4*i+0] + v.y*attw[DD+4*i+1] + v.z*attw[DD+4*i+2] + v.w*attw[DD+4*i+3];
    }
    s1[n] = a;
    s2[n] = b;
}

// KH: histogram of dst
__global__ __launch_bounds__(256) void kh_hist(
    const int* __restrict__ ei, int* __restrict__ count)
{
    int e = blockIdx.x * 256 + threadIdx.x;
    if (e >= NE) return;
    atomicAdd(count + ei[NE + e], 1);
}

// KSA/KSB/KSC: counting-sort scan
__global__ __launch_bounds__(256) void ks_scanA(
    const int* __restrict__ cnt, int* __restrict__ off, int* __restrict__ bsum)
{
    __shared__ int sa[256], sb[256];
    int t = threadIdx.x;
    int i = blockIdx.x * 256 + t;
    int v = (i < NN) ? cnt[i] : 0;
    sa[t] = v;
    __syncthreads();
    int* s = sa; int* d = sb;
    #pragma unroll
    for (int o = 1; o < 256; o <<= 1) {
        d[t] = s[t] + ((t >= o) ? s[t - o] : 0);
        __syncthreads();
        int* tmp = s; s = d; d = tmp;
    }
    int incl = s[t];
    if (i < NN) off[i] = incl - v;
    if (t == 255) bsum[blockIdx.x] = incl;
}

__global__ __launch_bounds__(512) void ks_scanB(int* __restrict__ bsum)
{
    __shared__ int sa[512], sb[512];
    int t = threadIdx.x;
    int v = (t < NB) ? bsum[t] : 0;
    sa[t] = v;
    __syncthreads();
    int* s = sa; int* d = sb;
    #pragma unroll
    for (int o = 1; o < 512; o <<= 1) {
        d[t] = s[t] + ((t >= o) ? s[t - o] : 0);
        __syncthreads();
        int* tmp = s; s = d; d = tmp;
    }
    if (t < NB) bsum[t] = s[t] - v;
}

__global__ __launch_bounds__(256) void ks_scanC(
    int* __restrict__ off, int* __restrict__ pos, const int* __restrict__ bsum)
{
    int i = blockIdx.x * 256 + threadIdx.x;
    if (i < NN) {
        int o = off[i] + bsum[blockIdx.x];
        off[i] = o;
        pos[i] = o;
    }
    if (i == 0) off[NN] = NE;
}

// KSCAT: scatter edges into dst-sorted order as {src (bits), rf}
__global__ __launch_bounds__(256) void kscat(
    const int* __restrict__ ei, const float* __restrict__ rf,
    int* __restrict__ pos, float2* __restrict__ sorted)
{
    int e = blockIdx.x * 256 + threadIdx.x;
    if (e >= NE) return;
    int src = ei[e];
    int dst = ei[NE + e];
    int p = atomicAdd(pos + dst, 1);
    sorted[p] = make_float2(__int_as_float(src), rf[e]);
}

// K4A: wave-per-node fused softmax + aggregation. uv[n] = {u, v}
__global__ __launch_bounds__(256) void k4a_agg(
    const float2* __restrict__ sorted, const int* __restrict__ off,
    const float* __restrict__ s1, const float* __restrict__ s2,
    const float* __restrict__ x, float* __restrict__ uv)
{
    int lane = threadIdx.x & 63;
    int n = blockIdx.x * 4 + (threadIdx.x >> 6);
    int r0 = off[n], r1 = off[n + 1];
    float s2n = s2[n];

    float m = -INFINITY, den = 0.f;
    for (int base = r0; base < r1; base += 64) {
        int idx = base + lane;
        float sc = -INFINITY;
        if (idx < r1) {
            float2 p = sorted[idx];
            sc = s1[__float_as_int(p.x)] + s2n;
        }
        float cm = wave_max64(sc);
        float nm = fmaxf(m, cm);
        float term = (idx < r1) ? __expf(sc - nm) : 0.f;
        den = den * __expf(m - nm) + wave_sum64(term);
        m = nm;
    }

    float u = 0.f, v = 0.f;
    for (int base = r0; base < r1; base += 64) {
        int idx = base + lane;
        int cnt = min(64, r1 - base);
        int srcl = 0; float rfl = 0.f, el = 0.f;
        if (idx < r1) {
            float2 p = sorted[idx];
            srcl = __float_as_int(p.x);
            rfl = p.y;
            el = __expf(s1[srcl] + s2n - m);
        }
        int j = 0;
        for (; j + 4 <= cnt; j += 4) {
            int   a0 = __shfl(srcl, j+0), a1 = __shfl(srcl, j+1);
            int   a2 = __shfl(srcl, j+2), a3 = __shfl(srcl, j+3);
            float e0 = __shfl(el, j+0), e1 = __shfl(el, j+1);
            float e2 = __shfl(el, j+2), e3 = __shfl(el, j+3);
            float f0 = __shfl(rfl, j+0), f1 = __shfl(rfl, j+1);
            float f2 = __shfl(rfl, j+2), f3 = __shfl(rfl, j+3);
            float x0 = x[(size_t)a0 * DD + lane];
            float x1 = x[(size_t)a1 * DD + lane];
            float x2 = x[(size_t)a2 * DD + lane];
            float x3 = x[(size_t)a3 * DD + lane];
            v += e0*x0 + e1*x1 + e2*x2 + e3*x3;
            u += e0*f0*x0 + e1*f1*x1 + e2*f2*x2 + e3*f3*x3;
        }
        for (; j < cnt; ++j) {
            int   sj = __shfl(srcl, j);
            float ej = __shfl(el,   j);
            float fj = __shfl(rfl,  j);
            float xv = x[(size_t)sj * DD + lane];
            v += ej * xv;
            u += ej * fj * xv;
        }
    }
    float inv = (r1 > r0) ? 1.f / den : 0.f;
    uv[(size_t)n * 2*DD + lane]      = u * inv;
    uv[(size_t)n * 2*DD + DD + lane] = v * inv;
}

// K4B: MFMA split-bf16 GEMM: agg[NN,64] = uv[NN,128] @ Bmix[128,64]
// Wave = 16 nodes; block = 4 waves = 64 nodes; no LDS.
__global__ __launch_bounds__(256) void k4b_mfma(
    const float* __restrict__ uv, const unsigned short* __restrict__ wh,
    const unsigned short* __restrict__ wl, float* __restrict__ agg)
{
    int lane = threadIdx.x & 63;
    int wv   = threadIdx.x >> 6;
    int quad = lane >> 4, l16 = lane & 15;
    int nb = blockIdx.x * 64 + wv * 16;
    const float* arow = uv + (size_t)(nb + l16) * 128;

    f32x4 acc[4] = {};
    #pragma unroll
    for (int ks = 0; ks < 4; ++ks) {
        int k0 = ks * 32 + quad * 8;
        short8 ah, al;
        split8(arow + k0, ah, al);
        #pragma unroll
        for (int nt = 0; nt < 4; ++nt) {
            short8 bh = *(const short8*)(wh + (size_t)(nt*16 + l16)*128 + k0);
            short8 bl = *(const short8*)(wl + (size_t)(nt*16 + l16)*128 + k0);
            acc[nt] = __builtin_amdgcn_mfma_f32_16x16x32_bf16(ah, bh, acc[nt], 0, 0, 0);
            acc[nt] = __builtin_amdgcn_mfma_f32_16x16x32_bf16(al, bh, acc[nt], 0, 0, 0);
            acc[nt] = __builtin_amdgcn_mfma_f32_16x16x32_bf16(ah, bl, acc[nt], 0, 0, 0);
        }
    }
    #pragma unroll
    for (int r = 0; r < 4; ++r) {
        int n = nb + quad * 4 + r;
        if (n < NN) {
            #pragma unroll
            for (int nt = 0; nt < 4; ++nt)
                agg[(size_t)n * 64 + nt*16 + l16] = acc[nt][r];
        }
    }
}

// K5H: h = LN1(gelu(agg) + x) -> hbuf (streaming, thread-per-node)
__global__ __launch_bounds__(256) void k5h_ln1(
    const float* __restrict__ agg, const float* __restrict__ x,
    const float* __restrict__ g1, const float* __restrict__ be1,
    float* __restrict__ hbuf)
{
    int n = blockIdx.x * 256 + threadIdx.x;
    if (n >= NN) return;
    float h[DD];
    const float4* a4 = (const float4*)(agg + (size_t)n * DD);
    const float4* x4 = (const float4*)(x   + (size_t)n * DD);
    #pragma unroll
    for (int i = 0; i < DD/4; ++i) {
        float4 av = a4[i];
        float4 xv = x4[i];
        h[4*i+0] = gelu_exact(av.x) + xv.x;
        h[4*i+1] = gelu_exact(av.y) + xv.y;
        h[4*i+2] = gelu_exact(av.z) + xv.z;
        h[4*i+3] = gelu_exact(av.w) + xv.w;
    }
    float mu = 0.f;
    #pragma unroll
    for (int d = 0; d < DD; ++d) mu += h[d];
    mu *= (1.0f/DD);
    float var = 0.f;
    #pragma unroll
    for (int d = 0; d < DD; ++d) { float t = h[d]-mu; var += t*t; }
    var *= (1.0f/DD);
    float rs = rsqrtf(var + 1e-5f);
    float4* h4 = (float4*)(hbuf + (size_t)n * DD);
    #pragma unroll
    for (int i = 0; i < DD/4; ++i) {
        float4 o;
        o.x = (h[4*i+0]-mu)*rs*g1[4*i+0] + be1[4*i+0];
        o.y = (h[4*i+1]-mu)*rs*g1[4*i+1] + be1[4*i+1];
        o.z = (h[4*i+2]-mu)*rs*g1[4*i+2] + be1[4*i+2];
        o.w = (h[4*i+3]-mu)*rs*g1[4*i+3] + be1[4*i+3];
        h4[i] = o;
    }
}

// K5A: MFMA GEMM1 + gelu: G[NN,128] = gelu(h[NN,64] @ w1^T + b1)
__global__ __launch_bounds__(256) void k5a_mfma(
    const float* __restrict__ hbuf, const unsigned short* __restrict__ w1h,
    const unsigned short* __restrict__ w1l, const float* __restrict__ bb1,
    float* __restrict__ G)
{
    int lane = threadIdx.x & 63;
    int wv   = threadIdx.x >> 6;
    int quad = lane >> 4, l16 = lane & 15;
    int nb = blockIdx.x * 64 + wv * 16;
    const float* arow = hbuf + (size_t)(nb + l16) * 64;

    f32x4 acc[8] = {};
    #pragma unroll
    for (int ks = 0; ks < 2; ++ks) {
        int k0 = ks * 32 + quad * 8;
        short8 ah, al;
        split8(arow + k0, ah, al);
        #pragma unroll
        for (int nt = 0; nt < 8; ++nt) {
            short8 bh = *(const short8*)(w1h + (size_t)(nt*16 + l16)*64 + k0);
            short8 bl = *(const short8*)(w1l + (size_t)(nt*16 + l16)*64 + k0);
            acc[nt] = __builtin_amdgcn_mfma_f32_16x16x32_bf16(ah, bh, acc[nt], 0, 0, 0);
            acc[nt] = __builtin_amdgcn_mfma_f32_16x16x32_bf16(al, bh, acc[nt], 0, 0, 0);
            acc[nt] = __builtin_amdgcn_mfma_f32_16x16x32_bf16(ah, bl, acc[nt], 0, 0, 0);
        }
    }
    #pragma unroll
    for (int nt = 0; nt < 8; ++nt) {
        float b1v = bb1[nt*16 + l16];
        #pragma unroll
        for (int r = 0; r < 4; ++r) {
            int n = nb + quad * 4 + r;
            if (n < NN)
                G[(size_t)n * 128 + nt*16 + l16] = gelu_exact(acc[nt][r] + b1v);
        }
    }
}

// K5B: MFMA GEMM2: mbuf[NN,64] = G[NN,128] @ w2^T
__global__ __launch_bounds__(256) void k5b_mfma(
    const float* __restrict__ G, const unsigned short* __restrict__ w2h,
    const unsigned short* __restrict__ w2l, float* __restrict__ mbuf)
{
    int lane = threadIdx.x & 63;
    int wv   = threadIdx.x >> 6;
    int quad = lane >> 4, l16 = lane & 15;
    int nb = blockIdx.x * 64 + wv * 16;
    const float* arow = G + (size_t)(nb + l16) * 128;

    f32x4 acc[4] = {};
    #pragma unroll
    for (int ks = 0; ks < 4; ++ks) {
        int k0 = ks * 32 + quad * 8;
        short8 ah, al;
        split8(arow + k0, ah, al);
        #pragma unroll
        for (int nt = 0; nt < 4; ++nt) {
            short8 bh = *(const short8*)(w2h + (size_t)(nt*16 + l16)*128 + k0);
            short8 bl = *(const short8*)(w2l + (size_t)(nt*16 + l16)*128 + k0);
            acc[nt] = __builtin_amdgcn_mfma_f32_16x16x32_bf16(ah, bh, acc[nt], 0, 0, 0);
            acc[nt] = __builtin_amdgcn_mfma_f32_16x16x32_bf16(al, bh, acc[nt], 0, 0, 0);
            acc[nt] = __builtin_amdgcn_mfma_f32_16x16x32_bf16(ah, bl, acc[nt], 0, 0, 0);
        }
    }
    #pragma unroll
    for (int r = 0; r < 4; ++r) {
        int n = nb + quad * 4 + r;
        if (n < NN) {
            #pragma unroll
            for (int nt = 0; nt < 4; ++nt)
                mbuf[(size_t)n * 64 + nt*16 + l16] = acc[nt][r];
        }
    }
}

// K5C: out = LN2(mbuf + hbuf + b2) (streaming, thread-per-node)
__global__ __launch_bounds__(256) void k5c_ln2(
    const float* __restrict__ mbuf, const float* __restrict__ hbuf,
    const float* __restrict__ bb2,
    const float* __restrict__ g2, const float* __restrict__ be2,
    float* __restrict__ out)
{
    int n = blockIdx.x * 256 + threadIdx.x;
    if (n >= NN) return;
    float m[DD];
    const float4* m4 = (const float4*)(mbuf + (size_t)n * DD);
    const float4* h4 = (const float4*)(hbuf + (size_t)n * DD);
    #pragma unroll
    for (int i = 0; i < DD/4; ++i) {
        float4 mv = m4[i];
        float4 hv = h4[i];
        m[4*i+0] = mv.x + hv.x + bb2[4*i+0];
        m[4*i+1] = mv.y + hv.y + bb2[4*i+1];
        m[4*i+2] = mv.z + hv.z + bb2[4*i+2];
        m[4*i+3] = mv.w + hv.w + bb2[4*i+3];
    }
    float mu = 0.f;
    #pragma unroll
    for (int d = 0; d < DD; ++d) mu += m[d];
    mu *= (1.0f/DD);
    float var = 0.f;
    #pragma unroll
    for (int d = 0; d < DD; ++d) { float t = m[d]-mu; var += t*t; }
    var *= (1.0f/DD);
    float rs = rsqrtf(var + 1e-5f);
    float4* o4 = (float4*)(out + (size_t)n * DD);
    #pragma unroll
    for (int i = 0; i < DD/4; ++i) {
        float4 o;
        o.x = (m[4*i+0]-mu)*rs*g2[4*i+0] + be2[4*i+0];
        o.y = (m[4*i+1]-mu)*rs*g2[4*i+1] + be2[4*i+1];
        o.z = (m[4*i+2]-mu)*rs*g2[4*i+2] + be2[4*i+2];
        o.w = (m[4*i+3]-mu)*rs*g2[4*i+3] + be2[4*i+3];
        o4[i] = o;
    }
}

extern "C" void kernel_launch(void* const* d_in, const int* in_sizes, int n_in,
                              void* d_out, int out_size, void* d_ws, size_t ws_size,
                              hipStream_t stream) {
    const float* x    = (const float*)d_in[0];
    const int*   ei   = (const int*)d_in[1];
    const float* rf   = (const float*)d_in[2];
    const float* Wp   = (const float*)d_in[3];
    const float* Wn   = (const float*)d_in[4];
    const float* attw = (const float*)d_in[5];
    const float* cf   = (const float*)d_in[6];
    const float* w1   = (const float*)d_in[7];
    const float* b1   = (const float*)d_in[8];
    const float* w2   = (const float*)d_in[9];
    const float* b2   = (const float*)d_in[10];
    const float* g1   = (const float*)d_in[11];
    const float* be1  = (const float*)d_in[12];
    const float* g2   = (const float*)d_in[13];
    const float* be2  = (const float*)d_in[14];
    float* out = (float*)d_out;

    float* ws = (float*)d_ws;
    float*  s1     = ws;                                   // NN
    float*  s2     = s1 + NN;                              // NN
    float*  uv     = s2 + NN;                              // NN*128
    float*  agg    = uv + (size_t)NN * 128;                // NN*64
    float*  hbuf   = agg + (size_t)NN * 64;                // NN*64
    unsigned short* wh = (unsigned short*)(hbuf + (size_t)NN * 64);  // 24576 u16
    unsigned short* wl = wh + 24576;                                 // 24576 u16
    float2* sorted = (float2*)(wl + 24576);                // NE float2
    int*    count  = (int*)(sorted + NE);                  // NN
    int*    off    = count + NN;                           // NN+1
    int*    pos    = off + NN + 1;                         // NN
    int*    bsum   = pos + NN;                             // 512
    float*  G      = uv;                                   // alias (uv dead after k4b)
    float*  mbuf   = agg;                                  // alias (agg dead after k5h)

    const unsigned short* wmh = wh;          const unsigned short* wml = wl;
    const unsigned short* w1h = wh + 8192;   const unsigned short* w1l = wl + 8192;
    const unsigned short* w2h = wh + 16384;  const unsigned short* w2l = wl + 16384;

    hipMemsetAsync(count, 0, NN * sizeof(int), stream);

    k0prep    <<<96, 256, 0, stream>>>(Wp, Wn, w1, w2, cf, wh, wl);
    k1_scores <<<(NN+255)/256, 256, 0, stream>>>(x, attw, s1, s2);
    kh_hist   <<<NE/256, 256, 0, stream>>>(ei, count);
    ks_scanA  <<<NB, 256, 0, stream>>>(count, off, bsum);
    ks_scanB  <<<1, 512, 0, stream>>>(bsum);
    ks_scanC  <<<NB, 256, 0, stream>>>(off, pos, bsum);
    kscat     <<<NE/256, 256, 0, stream>>>(ei, rf, pos, sorted);
    k4a_agg   <<<NN/4, 256, 0, stream>>>(sorted, off, s1, s2, x, uv);
    k4b_mfma  <<<(NN+63)/64, 256, 0, stream>>>(uv, wmh, wml, agg);
    k5h_ln1   <<<(NN+255)/256, 256, 0, stream>>>(agg, x, g1, be1, hbuf);
    k5a_mfma  <<<(NN+63)/64, 256, 0, stream>>>(hbuf, w1h, w1l, b1, G);
    k5b_mfma  <<<(NN+63)/64, 256, 0, stream>>>(G, w2h, w2l, mbuf);
    k5c_ln2   <<<(NN+255)/256, 256, 0, stream>>>(mbuf, hbuf, b2, g2, be2, out);
}